// Round 2
// baseline (1417.968 us; speedup 1.0000x reference)
//
#include <hip/hip_runtime.h>
#include <hip/hip_fp16.h>

// AGCRN cell on MI355X. fp16 MFMA (16x16x32) + fp32 accum; fp32 nonlinearities.
// Round 2: precompute per-node weights W[n][kc][o][i] (fp16) with a dedicated
// GEMM-shaped kernel instead of recomputing E[n]·pool inside k_gate/k_update
// (which was 453us at MfmaUtil 1.2%). Fallback to in-kernel W if ws too small.

#define B_  64
#define N_  2048
#define D_  16
#define CO_ 64
#define CC_ 128   // concat channels (in+out)

typedef _Float16 f16x8 __attribute__((ext_vector_type(8)));
typedef float    f32x4 __attribute__((ext_vector_type(4)));

static __device__ __forceinline__ uint pack2(float a, float b) {
  return (uint)__half_as_ushort(__float2half(a)) |
         ((uint)__half_as_ushort(__float2half(b)) << 16);
}

// ---------------------------------------------------------------------------
// A = softmax(relu(E E^T)) row-wise, stored fp16. One block per row.
__global__ __launch_bounds__(256)
void k_softmaxA(const float* __restrict__ E, __half* __restrict__ A) {
  const int n = blockIdx.x, t = threadIdx.x;
  __shared__ float row[N_];
  __shared__ float red[4];
  const float4* en4 = reinterpret_cast<const float4*>(E + n * D_);
  const float4 e0 = en4[0], e1 = en4[1], e2 = en4[2], e3 = en4[3];
  float lmax = 0.f;  // relu => scores >= 0
  for (int m = t; m < N_; m += 256) {
    const float4* em4 = reinterpret_cast<const float4*>(E + m * D_);
    const float4 f0 = em4[0], f1 = em4[1], f2 = em4[2], f3 = em4[3];
    float d = e0.x*f0.x + e0.y*f0.y + e0.z*f0.z + e0.w*f0.w
            + e1.x*f1.x + e1.y*f1.y + e1.z*f1.z + e1.w*f1.w
            + e2.x*f2.x + e2.y*f2.y + e2.z*f2.z + e2.w*f2.w
            + e3.x*f3.x + e3.y*f3.y + e3.z*f3.z + e3.w*f3.w;
    d = fmaxf(d, 0.f);
    row[m] = d;
    lmax = fmaxf(lmax, d);
  }
  #pragma unroll
  for (int off = 32; off > 0; off >>= 1) lmax = fmaxf(lmax, __shfl_down(lmax, off));
  __syncthreads();
  if ((t & 63) == 0) red[t >> 6] = lmax;
  __syncthreads();
  const float gmax = fmaxf(fmaxf(red[0], red[1]), fmaxf(red[2], red[3]));
  float lsum = 0.f;
  for (int m = t; m < N_; m += 256) {
    float v = __expf(row[m] - gmax);
    row[m] = v;
    lsum += v;
  }
  #pragma unroll
  for (int off = 32; off > 0; off >>= 1) lsum += __shfl_down(lsum, off);
  __syncthreads();
  if ((t & 63) == 0) red[t >> 6] = lsum;
  __syncthreads();
  const float rinv = 1.f / (red[0] + red[1] + red[2] + red[3]);
  for (int m = t; m < N_; m += 256)
    A[(long)n * N_ + m] = __float2half(row[m] * rinv);
}

// ---------------------------------------------------------------------------
// Generic f16 GEMM: C = op(A @ B). Tile 128x128, BK=32, 4 waves.
// MODE 0: C=v. MODE 1: C = 2v - I. blockIdx.z batches B/C via strides.
template <int MODE>
__global__ __launch_bounds__(256)
void k_gemm(const __half* __restrict__ Ag, const __half* __restrict__ Bg,
            __half* __restrict__ Cg, int K, int lda, int ldb, int ldc,
            long sB, long sC) {
  const int m0 = blockIdx.x * 128;
  const int n0 = blockIdx.y * 128;
  Bg += (long)blockIdx.z * sB;
  Cg += (long)blockIdx.z * sC;
  __shared__ __half As[128][40];
  __shared__ __half Bs[128][40];
  const int t = threadIdx.x, lane = t & 63, wid = t >> 6;
  const int wm = (wid & 1) * 64, wn = (wid >> 1) * 64;
  f32x4 acc[4][4] = {};
  const int ar = t >> 1, aseg = t & 1;
  const int bc = t & 127, bkg = (t >> 7) * 8;

  for (int kt = 0; kt < K; kt += 32) {
    {
      const uint4* asrc = reinterpret_cast<const uint4*>(
          Ag + (long)(m0 + ar) * lda + kt + aseg * 16);
      uint4 av0 = asrc[0], av1 = asrc[1];
      *reinterpret_cast<uint4*>(&As[ar][aseg * 16])     = av0;
      *reinterpret_cast<uint4*>(&As[ar][aseg * 16 + 8]) = av1;
    }
    #pragma unroll
    for (int it = 0; it < 2; ++it) {
      const int kk = bkg + it * 16;
      const __half* bsrc = Bg + (long)(kt + kk) * ldb + n0 + bc;
      ushort h[8];
      #pragma unroll
      for (int j = 0; j < 8; ++j) h[j] = __half_as_ushort(bsrc[(long)j * ldb]);
      uint4 pk;
      pk.x = (uint)h[0] | ((uint)h[1] << 16);
      pk.y = (uint)h[2] | ((uint)h[3] << 16);
      pk.z = (uint)h[4] | ((uint)h[5] << 16);
      pk.w = (uint)h[6] | ((uint)h[7] << 16);
      *reinterpret_cast<uint4*>(&Bs[bc][kk]) = pk;
    }
    __syncthreads();
    f16x8 af[4], bf[4];
    #pragma unroll
    for (int i = 0; i < 4; ++i) {
      af[i] = *reinterpret_cast<const f16x8*>(&As[wm + i * 16 + (lane & 15)][(lane >> 4) * 8]);
      bf[i] = *reinterpret_cast<const f16x8*>(&Bs[wn + i * 16 + (lane & 15)][(lane >> 4) * 8]);
    }
    #pragma unroll
    for (int i = 0; i < 4; ++i)
      #pragma unroll
      for (int j = 0; j < 4; ++j)
        acc[i][j] = __builtin_amdgcn_mfma_f32_16x16x32_f16(af[i], bf[j], acc[i][j], 0, 0, 0);
    __syncthreads();
  }
  const int cr = (lane >> 4) * 4, ccol = lane & 15;
  #pragma unroll
  for (int i = 0; i < 4; ++i)
    #pragma unroll
    for (int j = 0; j < 4; ++j) {
      const int gr = m0 + wm + i * 16 + cr;
      const int gc = n0 + wn + j * 16 + ccol;
      #pragma unroll
      for (int r = 0; r < 4; ++r) {
        float v = acc[i][j][r];
        if (MODE == 1) v = 2.f * v - ((gr + r) == gc ? 1.f : 0.f);
        Cg[(long)(gr + r) * ldc + gc] = __float2half(v);
      }
    }
}

// ---------------------------------------------------------------------------
// W precompute: W[n][kc][o][i] = sum_d E[n,d] * pool[d][kc][i][o], fp16 out.
// Block: 32 n-rows x 512 cols (one kc, 4 o's, full i=0..127). Thread: 8x8 acc.
// PoolS chunk layout: 8-float chunks at stride 12 dwords -> b128 reads hit all
// 32 banks (8/bank = b128 floor).
template <int OSZ>
__global__ __launch_bounds__(256)
void k_wpre(const float* __restrict__ pool, const float* __restrict__ E,
            __half* __restrict__ W) {
  const int WC = 3 * OSZ * 128;
  const int col0 = blockIdx.x * 512;
  const int kc = col0 / (OSZ * 128);
  const int o0 = (col0 - kc * OSZ * 128) >> 7;
  const int n0 = blockIdx.y * 32;
  const int t = threadIdx.x;
  __shared__ float PoolS[16 * 768];  // 64 chunks * 12 dwords per d-row
  __shared__ float Es[32][16];
  for (int p = t; p < 512; p += 256)
    Es[p >> 4][p & 15] = E[(n0 + (p >> 4)) * 16 + (p & 15)];
  for (int p = t; p < 16 * 512; p += 256) {
    const int d = p >> 9, jl = p & 511;
    const int o = o0 + (jl >> 7), i = jl & 127;
    PoolS[d * 768 + (jl >> 3) * 12 + (jl & 7)] =
        pool[((long)(d * 3 + kc) * 128 + i) * OSZ + o];
  }
  __syncthreads();
  const int c8 = (t & 63) * 8;         // col chunk base (8 cols)
  const int r0 = (t >> 6) * 8;         // row group (8 rows)
  const int cbase = (t & 63) * 12;     // LDS dword base of this chunk
  float acc[8][8] = {};
  #pragma unroll
  for (int d = 0; d < 16; ++d) {
    const float4 pv0 = *reinterpret_cast<const float4*>(&PoolS[d * 768 + cbase]);
    const float4 pv1 = *reinterpret_cast<const float4*>(&PoolS[d * 768 + cbase + 4]);
    #pragma unroll
    for (int rr = 0; rr < 8; ++rr) {
      const float e = Es[r0 + rr][d];
      acc[rr][0] += e * pv0.x; acc[rr][1] += e * pv0.y;
      acc[rr][2] += e * pv0.z; acc[rr][3] += e * pv0.w;
      acc[rr][4] += e * pv1.x; acc[rr][5] += e * pv1.y;
      acc[rr][6] += e * pv1.z; acc[rr][7] += e * pv1.w;
    }
  }
  #pragma unroll
  for (int rr = 0; rr < 8; ++rr) {
    uint4 pk;
    pk.x = pack2(acc[rr][0], acc[rr][1]);
    pk.y = pack2(acc[rr][2], acc[rr][3]);
    pk.z = pack2(acc[rr][4], acc[rr][5]);
    pk.w = pack2(acc[rr][6], acc[rr][7]);
    *reinterpret_cast<uint4*>(W + (long)(n0 + r0 + rr) * WC + col0 + c8) = pk;
  }
}

// ---------------------------------------------------------------------------
// XH[b][n][0:64]=X, [64:128]=H  (fp32 -> fp16)
__global__ __launch_bounds__(256)
void k_build_xh(const float* __restrict__ X, const float* __restrict__ H,
                __half* __restrict__ XH) {
  const long i = (long)blockIdx.x * 256 + threadIdx.x;  // quad id: B*N*32
  const long bn = i >> 5;
  const int  q  = (int)(i & 31);
  const float* src = (q < 16 ? X : H) + bn * 64 + (q & 15) * 4;
  const float4 v = *reinterpret_cast<const float4*>(src);
  ushort4 h;
  h.x = __half_as_ushort(__float2half(v.x));
  h.y = __half_as_ushort(__float2half(v.y));
  h.z = __half_as_ushort(__float2half(v.z));
  h.w = __half_as_ushort(__float2half(v.w));
  *reinterpret_cast<ushort4*>(XH + bn * CC_ + q * 4) = h;
}

// fp32 -> fp16 cast (fallback pools only)
__global__ __launch_bounds__(256)
void k_cast_f16(const float* __restrict__ src, __half* __restrict__ dst, int nquads) {
  const int i = blockIdx.x * 256 + threadIdx.x;
  if (i >= nquads) return;
  const float4 v = reinterpret_cast<const float4*>(src)[i];
  ushort4 h;
  h.x = __half_as_ushort(__float2half(v.x));
  h.y = __half_as_ushort(__float2half(v.y));
  h.z = __half_as_ushort(__float2half(v.z));
  h.w = __half_as_ushort(__float2half(v.w));
  *reinterpret_cast<ushort4*>(dst + i * 4) = h;
}

// bias[n][o] = sum_d E[n][d] * pool[d][o]
__global__ __launch_bounds__(256)
void k_bias(const float* __restrict__ E, const float* __restrict__ pool,
            float* __restrict__ bias, int O) {
  const int idx = blockIdx.x * 256 + threadIdx.x;
  const int n = idx / O, o = idx - n * O;
  float s = 0.f;
  #pragma unroll
  for (int d = 0; d < D_; ++d) s += E[n * D_ + d] * pool[d * O + o];
  bias[idx] = s;
}

// ---------------------------------------------------------------------------
// Gate: per node n, ZR[64b x 128o] = sum_k XGk @ Wk, sigmoid; Z*H into XH
// (becomes C), R -> Rbuf. PRE: Wsrc = precomputed W[n][kc][o][i] fp16.
// !PRE: Wsrc = fp16 pool, compute W in-kernel (fallback).
template <bool PRE>
__global__ __launch_bounds__(256)
void k_gate(const __half* __restrict__ XH, const __half* __restrict__ G1,
            const __half* __restrict__ G2, const __half* __restrict__ Wsrc,
            const float* __restrict__ E, const float* __restrict__ bg,
            const float* __restrict__ H, __half* __restrict__ XHw,
            float* __restrict__ R) {
  const int n = blockIdx.x, t = threadIdx.x, lane = t & 63, wid = t >> 6;
  __shared__ __half Ws[128][136];
  __shared__ __half Ds[64][136];
  __shared__ float es[D_];
  if constexpr (!PRE) {
    if (t < D_) es[t] = E[n * D_ + t];
    __syncthreads();
  }
  f32x4 acc[4][2] = {};
  const __half* srcs[3] = {XH, G1, G2};
  #pragma unroll
  for (int kc = 0; kc < 3; ++kc) {
    {  // stage data tile: XGkc[:, n, :]  (64 x 128)
      const int b = t & 63, seg = t >> 6;
      const uint4* s = reinterpret_cast<const uint4*>(
          srcs[kc] + ((long)b * N_ + n) * CC_ + seg * 32);
      uint4 v0 = s[0], v1 = s[1], v2 = s[2], v3 = s[3];
      uint4* d = reinterpret_cast<uint4*>(&Ds[b][seg * 32]);
      d[0] = v0; d[1] = v1; d[2] = v2; d[3] = v3;
    }
    if constexpr (PRE) {
      // stage W chunk: straight coalesced copy, 128x128 halves
      const uint4* s4 = reinterpret_cast<const uint4*>(
          Wsrc + ((long)(n * 3 + kc) * 128 + (t >> 1)) * 128 + (t & 1) * 64);
      uint4* dst = reinterpret_cast<uint4*>(&Ws[t >> 1][(t & 1) * 64]);
      #pragma unroll
      for (int q = 0; q < 8; ++q) dst[q] = s4[q];
    } else {
      const __half* pk = Wsrc + (long)kc * 128 * 128;
      for (int p = t; p < 64 * 128; p += 256) {
        const int o2 = p & 63, i = p >> 6;
        float w0 = 0.f, w1 = 0.f;
        #pragma unroll
        for (int d = 0; d < D_; ++d) {
          const __half2 h2 = *reinterpret_cast<const __half2*>(
              pk + (long)d * 3 * 128 * 128 + i * 128 + o2 * 2);
          const float e = es[d];
          w0 += e * __half2float(h2.x);
          w1 += e * __half2float(h2.y);
        }
        Ws[o2 * 2][i]     = __float2half(w0);
        Ws[o2 * 2 + 1][i] = __float2half(w1);
      }
    }
    __syncthreads();
    #pragma unroll
    for (int ks = 0; ks < 4; ++ks) {
      f16x8 a[4], bf[2];
      #pragma unroll
      for (int i = 0; i < 4; ++i)
        a[i] = *reinterpret_cast<const f16x8*>(&Ds[i * 16 + (lane & 15)][ks * 32 + (lane >> 4) * 8]);
      #pragma unroll
      for (int j = 0; j < 2; ++j)
        bf[j] = *reinterpret_cast<const f16x8*>(&Ws[wid * 32 + j * 16 + (lane & 15)][ks * 32 + (lane >> 4) * 8]);
      #pragma unroll
      for (int i = 0; i < 4; ++i)
        #pragma unroll
        for (int j = 0; j < 2; ++j)
          acc[i][j] = __builtin_amdgcn_mfma_f32_16x16x32_f16(a[i], bf[j], acc[i][j], 0, 0, 0);
    }
    __syncthreads();
  }
  const int cr = (lane >> 4) * 4, co = lane & 15;
  #pragma unroll
  for (int i = 0; i < 4; ++i)
    #pragma unroll
    for (int j = 0; j < 2; ++j) {
      const int o = wid * 32 + j * 16 + co;
      const float bv = bg[n * 128 + o];
      #pragma unroll
      for (int r = 0; r < 4; ++r) {
        const int b = i * 16 + cr + r;
        const float v = acc[i][j][r] + bv;
        const float s = 1.f / (1.f + __expf(-v));
        const long base = ((long)b * N_ + n) * CO_ + (o & 63);
        if (o < 64) {
          XHw[((long)b * N_ + n) * CC_ + 64 + o] = __float2half(s * H[base]);
        } else {
          R[base] = s;
        }
      }
    }
}

// ---------------------------------------------------------------------------
// Update: per node n, HCpre[64b x 64o] = sum_k XGk @ Wk; out = R*H+(1-R)*tanh
template <bool PRE>
__global__ __launch_bounds__(256)
void k_update(const __half* __restrict__ C, const __half* __restrict__ G1,
              const __half* __restrict__ G2, const __half* __restrict__ Wsrc,
              const float* __restrict__ E, const float* __restrict__ bu,
              const float* __restrict__ H, const float* __restrict__ R,
              float* __restrict__ out) {
  const int n = blockIdx.x, t = threadIdx.x, lane = t & 63, wid = t >> 6;
  __shared__ __half Ws[64][136];
  __shared__ __half Ds[64][136];
  __shared__ float es[D_];
  if constexpr (!PRE) {
    if (t < D_) es[t] = E[n * D_ + t];
    __syncthreads();
  }
  f32x4 acc[4] = {};
  const __half* srcs[3] = {C, G1, G2};
  #pragma unroll
  for (int kc = 0; kc < 3; ++kc) {
    {
      const int b = t & 63, seg = t >> 6;
      const uint4* s = reinterpret_cast<const uint4*>(
          srcs[kc] + ((long)b * N_ + n) * CC_ + seg * 32);
      uint4 v0 = s[0], v1 = s[1], v2 = s[2], v3 = s[3];
      uint4* d = reinterpret_cast<uint4*>(&Ds[b][seg * 32]);
      d[0] = v0; d[1] = v1; d[2] = v2; d[3] = v3;
    }
    if constexpr (PRE) {
      const uint4* s4 = reinterpret_cast<const uint4*>(
          Wsrc + ((long)(n * 3 + kc) * 64 + (t >> 2)) * 128 + (t & 3) * 32);
      uint4* dst = reinterpret_cast<uint4*>(&Ws[t >> 2][(t & 3) * 32]);
      #pragma unroll
      for (int q = 0; q < 4; ++q) dst[q] = s4[q];
    } else {
      const __half* pk = Wsrc + (long)kc * 128 * 64;
      for (int p = t; p < 32 * 128; p += 256) {
        const int o2 = p & 31, i = p >> 5;
        float w0 = 0.f, w1 = 0.f;
        #pragma unroll
        for (int d = 0; d < D_; ++d) {
          const __half2 h2 = *reinterpret_cast<const __half2*>(
              pk + (long)d * 3 * 128 * 64 + i * 64 + o2 * 2);
          const float e = es[d];
          w0 += e * __half2float(h2.x);
          w1 += e * __half2float(h2.y);
        }
        Ws[o2 * 2][i]     = __float2half(w0);
        Ws[o2 * 2 + 1][i] = __float2half(w1);
      }
    }
    __syncthreads();
    #pragma unroll
    for (int ks = 0; ks < 4; ++ks) {
      f16x8 a[4], bf;
      #pragma unroll
      for (int i = 0; i < 4; ++i)
        a[i] = *reinterpret_cast<const f16x8*>(&Ds[i * 16 + (lane & 15)][ks * 32 + (lane >> 4) * 8]);
      bf = *reinterpret_cast<const f16x8*>(&Ws[wid * 16 + (lane & 15)][ks * 32 + (lane >> 4) * 8]);
      #pragma unroll
      for (int i = 0; i < 4; ++i)
        acc[i] = __builtin_amdgcn_mfma_f32_16x16x32_f16(a[i], bf, acc[i], 0, 0, 0);
    }
    __syncthreads();
  }
  const int cr = (lane >> 4) * 4, co = lane & 15;
  const int o = wid * 16 + co;
  const float bv = bu[n * 64 + o];
  #pragma unroll
  for (int i = 0; i < 4; ++i)
    #pragma unroll
    for (int r = 0; r < 4; ++r) {
      const int b = i * 16 + cr + r;
      const long idx = ((long)b * N_ + n) * CO_ + o;
      const float hc = tanhf(acc[i][r] + bv);
      const float rr = R[idx];
      out[idx] = rr * H[idx] + (1.f - rr) * hc;
    }
}

// ---------------------------------------------------------------------------
extern "C" void kernel_launch(void* const* d_in, const int* in_sizes, int n_in,
                              void* d_out, int out_size, void* d_ws, size_t ws_size,
                              hipStream_t stream) {
  const float* X  = (const float*)d_in[0];
  const float* E  = (const float*)d_in[1];
  const float* H  = (const float*)d_in[2];
  const float* gp = (const float*)d_in[3];  // [16][3][128][128]
  const float* gb = (const float*)d_in[4];  // [16][128]
  const float* up = (const float*)d_in[5];  // [16][3][128][64]
  const float* ub = (const float*)d_in[6];  // [16][64]
  float* out = (float*)d_out;

  size_t off = 0;
  auto alloc = [&](size_t bytes) {
    void* p = (char*)d_ws + off;
    off += (bytes + 255) & ~(size_t)255;
    return p;
  };
  __half* A16  = (__half*)alloc((size_t)N_ * N_ * 2);
  __half* S16  = (__half*)alloc((size_t)N_ * N_ * 2);
  __half* XH   = (__half*)alloc((size_t)B_ * N_ * CC_ * 2);
  __half* G1   = (__half*)alloc((size_t)B_ * N_ * CC_ * 2);
  __half* G2   = (__half*)alloc((size_t)B_ * N_ * CC_ * 2);
  float*  Rbuf = (float*)alloc((size_t)B_ * N_ * CO_ * 4);
  float*  bg   = (float*)alloc((size_t)N_ * 128 * 4);
  float*  bu   = (float*)alloc((size_t)N_ * 64 * 4);

  const size_t wbytes = (size_t)N_ * 3 * 128 * 128 * 2;  // gate W (update aliases)
  __half* Wbuf = (__half*)((char*)d_ws + off);
  const bool pre = (off + wbytes) <= ws_size;

  const long sXH = (long)N_ * CC_;

  k_bias<<<1024, 256, 0, stream>>>(E, gb, bg, 128);
  k_bias<<<512, 256, 0, stream>>>(E, ub, bu, 64);
  k_softmaxA<<<N_, 256, 0, stream>>>(E, A16);
  k_gemm<1><<<dim3(16, 16, 1), 256, 0, stream>>>(A16, A16, S16, N_, N_, N_, N_, 0, 0);
  k_build_xh<<<16384, 256, 0, stream>>>(X, H, XH);

  if (pre) {
    k_wpre<128><<<dim3(96, 64), 256, 0, stream>>>(gp, E, Wbuf);
    k_gemm<0><<<dim3(16, 1, B_), 256, 0, stream>>>(A16, XH, G1, N_, N_, CC_, CC_, sXH, sXH);
    k_gemm<0><<<dim3(16, 1, B_), 256, 0, stream>>>(S16, XH, G2, N_, N_, CC_, CC_, sXH, sXH);
    k_gate<true><<<N_, 256, 0, stream>>>(XH, G1, G2, Wbuf, E, bg, H, XH, Rbuf);
    k_wpre<64><<<dim3(48, 64), 256, 0, stream>>>(up, E, Wbuf);  // after gate consumed Wg
    k_gemm<0><<<dim3(16, 1, B_), 256, 0, stream>>>(A16, XH, G1, N_, N_, CC_, CC_, sXH, sXH);
    k_gemm<0><<<dim3(16, 1, B_), 256, 0, stream>>>(S16, XH, G2, N_, N_, CC_, CC_, sXH, sXH);
    k_update<true><<<N_, 256, 0, stream>>>(XH, G1, G2, Wbuf, E, bu, H, Rbuf, out);
  } else {
    __half* pg = (__half*)alloc((size_t)D_ * 3 * 128 * 128 * 2);
    __half* pu = (__half*)alloc((size_t)D_ * 3 * 128 * 64 * 2);
    k_cast_f16<<<768, 256, 0, stream>>>(gp, pg, 196608);
    k_cast_f16<<<384, 256, 0, stream>>>(up, pu, 98304);
    k_gemm<0><<<dim3(16, 1, B_), 256, 0, stream>>>(A16, XH, G1, N_, N_, CC_, CC_, sXH, sXH);
    k_gemm<0><<<dim3(16, 1, B_), 256, 0, stream>>>(S16, XH, G2, N_, N_, CC_, CC_, sXH, sXH);
    k_gate<false><<<N_, 256, 0, stream>>>(XH, G1, G2, pg, E, bg, H, XH, Rbuf);
    k_gemm<0><<<dim3(16, 1, B_), 256, 0, stream>>>(A16, XH, G1, N_, N_, CC_, CC_, sXH, sXH);
    k_gemm<0><<<dim3(16, 1, B_), 256, 0, stream>>>(S16, XH, G2, N_, N_, CC_, CC_, sXH, sXH);
    k_update<false><<<N_, 256, 0, stream>>>(XH, G1, G2, pu, E, bu, H, Rbuf, out);
  }
}

// Round 3
// 1013.714 us; speedup vs baseline: 1.3988x; 1.3988x over previous
//
#include <hip/hip_runtime.h>
#include <hip/hip_fp16.h>

// AGCRN cell on MI355X. fp16 MFMA (16x16x32) + fp32 accum; fp32 nonlinearities.
// Round 3: (a) node-chunked W precompute sized from ws_size at launch time
// (round-2's single 201MB W buffer exceeded ws_size -> fallback silently ran);
// (b) eliminate S2 buffer+GEMM via S2@X = 2*A@(A@X) - X folded into staging;
// (c) R buffer fp16. Base working set 127.4MB; W chunks use the remainder.

#define B_  64
#define N_  2048
#define D_  16
#define CO_ 64
#define CC_ 128   // concat channels (in+out)

typedef _Float16 f16x8 __attribute__((ext_vector_type(8)));
typedef float    f32x4 __attribute__((ext_vector_type(4)));

static __device__ __forceinline__ uint pack2(float a, float b) {
  return (uint)__half_as_ushort(__float2half(a)) |
         ((uint)__half_as_ushort(__float2half(b)) << 16);
}

// ---------------------------------------------------------------------------
// A = softmax(relu(E E^T)) row-wise, stored fp16. One block per row.
__global__ __launch_bounds__(256)
void k_softmaxA(const float* __restrict__ E, __half* __restrict__ A) {
  const int n = blockIdx.x, t = threadIdx.x;
  __shared__ float row[N_];
  __shared__ float red[4];
  const float4* en4 = reinterpret_cast<const float4*>(E + n * D_);
  const float4 e0 = en4[0], e1 = en4[1], e2 = en4[2], e3 = en4[3];
  float lmax = 0.f;  // relu => scores >= 0
  for (int m = t; m < N_; m += 256) {
    const float4* em4 = reinterpret_cast<const float4*>(E + m * D_);
    const float4 f0 = em4[0], f1 = em4[1], f2 = em4[2], f3 = em4[3];
    float d = e0.x*f0.x + e0.y*f0.y + e0.z*f0.z + e0.w*f0.w
            + e1.x*f1.x + e1.y*f1.y + e1.z*f1.z + e1.w*f1.w
            + e2.x*f2.x + e2.y*f2.y + e2.z*f2.z + e2.w*f2.w
            + e3.x*f3.x + e3.y*f3.y + e3.z*f3.z + e3.w*f3.w;
    d = fmaxf(d, 0.f);
    row[m] = d;
    lmax = fmaxf(lmax, d);
  }
  #pragma unroll
  for (int off = 32; off > 0; off >>= 1) lmax = fmaxf(lmax, __shfl_down(lmax, off));
  __syncthreads();
  if ((t & 63) == 0) red[t >> 6] = lmax;
  __syncthreads();
  const float gmax = fmaxf(fmaxf(red[0], red[1]), fmaxf(red[2], red[3]));
  float lsum = 0.f;
  for (int m = t; m < N_; m += 256) {
    float v = __expf(row[m] - gmax);
    row[m] = v;
    lsum += v;
  }
  #pragma unroll
  for (int off = 32; off > 0; off >>= 1) lsum += __shfl_down(lsum, off);
  __syncthreads();
  if ((t & 63) == 0) red[t >> 6] = lsum;
  __syncthreads();
  const float rinv = 1.f / (red[0] + red[1] + red[2] + red[3]);
  for (int m = t; m < N_; m += 256)
    A[(long)n * N_ + m] = __float2half(row[m] * rinv);
}

// ---------------------------------------------------------------------------
// f16 GEMM: C = A @ B. Tile 128x128, BK=32, 4 waves. blockIdx.z batches B/C.
__global__ __launch_bounds__(256)
void k_gemm(const __half* __restrict__ Ag, const __half* __restrict__ Bg,
            __half* __restrict__ Cg, int K, int lda, int ldb, int ldc,
            long sB, long sC) {
  const int m0 = blockIdx.x * 128;
  const int n0 = blockIdx.y * 128;
  Bg += (long)blockIdx.z * sB;
  Cg += (long)blockIdx.z * sC;
  __shared__ __half As[128][40];
  __shared__ __half Bs[128][40];
  const int t = threadIdx.x, lane = t & 63, wid = t >> 6;
  const int wm = (wid & 1) * 64, wn = (wid >> 1) * 64;
  f32x4 acc[4][4] = {};
  const int ar = t >> 1, aseg = t & 1;
  const int bc = t & 127, bkg = (t >> 7) * 8;

  for (int kt = 0; kt < K; kt += 32) {
    {
      const uint4* asrc = reinterpret_cast<const uint4*>(
          Ag + (long)(m0 + ar) * lda + kt + aseg * 16);
      uint4 av0 = asrc[0], av1 = asrc[1];
      *reinterpret_cast<uint4*>(&As[ar][aseg * 16])     = av0;
      *reinterpret_cast<uint4*>(&As[ar][aseg * 16 + 8]) = av1;
    }
    #pragma unroll
    for (int it = 0; it < 2; ++it) {
      const int kk = bkg + it * 16;
      const __half* bsrc = Bg + (long)(kt + kk) * ldb + n0 + bc;
      ushort h[8];
      #pragma unroll
      for (int j = 0; j < 8; ++j) h[j] = __half_as_ushort(bsrc[(long)j * ldb]);
      uint4 pk;
      pk.x = (uint)h[0] | ((uint)h[1] << 16);
      pk.y = (uint)h[2] | ((uint)h[3] << 16);
      pk.z = (uint)h[4] | ((uint)h[5] << 16);
      pk.w = (uint)h[6] | ((uint)h[7] << 16);
      *reinterpret_cast<uint4*>(&Bs[bc][kk]) = pk;
    }
    __syncthreads();
    f16x8 af[4], bf[4];
    #pragma unroll
    for (int i = 0; i < 4; ++i) {
      af[i] = *reinterpret_cast<const f16x8*>(&As[wm + i * 16 + (lane & 15)][(lane >> 4) * 8]);
      bf[i] = *reinterpret_cast<const f16x8*>(&Bs[wn + i * 16 + (lane & 15)][(lane >> 4) * 8]);
    }
    #pragma unroll
    for (int i = 0; i < 4; ++i)
      #pragma unroll
      for (int j = 0; j < 4; ++j)
        acc[i][j] = __builtin_amdgcn_mfma_f32_16x16x32_f16(af[i], bf[j], acc[i][j], 0, 0, 0);
    __syncthreads();
  }
  const int cr = (lane >> 4) * 4, ccol = lane & 15;
  #pragma unroll
  for (int i = 0; i < 4; ++i)
    #pragma unroll
    for (int j = 0; j < 4; ++j) {
      const int gr = m0 + wm + i * 16 + cr;
      const int gc = n0 + wn + j * 16 + ccol;
      #pragma unroll
      for (int r = 0; r < 4; ++r)
        Cg[(long)(gr + r) * ldc + gc] = __float2half(acc[i][j][r]);
    }
}

// ---------------------------------------------------------------------------
// W precompute for a node chunk: W[nloc][kc][o][i] = sum_d E[n0+nloc,d]*pool[d][kc][i][o].
// Block: 32 nodes x 512 cols (one kc, 4 o's, i=0..127). Thread: 8x8 acc.
template <int OSZ>
__global__ __launch_bounds__(256)
void k_wpre(const float* __restrict__ pool, const float* __restrict__ E,
            __half* __restrict__ W, int n0) {
  const int WC = 3 * OSZ * 128;
  const int col0 = blockIdx.x * 512;
  const int kc = col0 / (OSZ * 128);
  const int o0 = (col0 - kc * OSZ * 128) >> 7;
  const int t = threadIdx.x;
  __shared__ float PoolS[16 * 768];  // 64 chunks * 12 dwords per d-row (16B-aligned)
  __shared__ float Es[32][16];
  for (int p = t; p < 512; p += 256)
    Es[p >> 4][p & 15] = E[(n0 + blockIdx.y * 32 + (p >> 4)) * 16 + (p & 15)];
  for (int p = t; p < 16 * 512; p += 256) {
    const int d = p >> 9, jl = p & 511;
    const int o = o0 + (jl >> 7), i = jl & 127;
    PoolS[d * 768 + (jl >> 3) * 12 + (jl & 7)] =
        pool[((long)(d * 3 + kc) * 128 + i) * OSZ + o];
  }
  __syncthreads();
  const int c8 = (t & 63) * 8;
  const int r0 = (t >> 6) * 8;
  const int cbase = (t & 63) * 12;
  float acc[8][8] = {};
  #pragma unroll
  for (int d = 0; d < 16; ++d) {
    const float4 pv0 = *reinterpret_cast<const float4*>(&PoolS[d * 768 + cbase]);
    const float4 pv1 = *reinterpret_cast<const float4*>(&PoolS[d * 768 + cbase + 4]);
    #pragma unroll
    for (int rr = 0; rr < 8; ++rr) {
      const float e = Es[r0 + rr][d];
      acc[rr][0] += e * pv0.x; acc[rr][1] += e * pv0.y;
      acc[rr][2] += e * pv0.z; acc[rr][3] += e * pv0.w;
      acc[rr][4] += e * pv1.x; acc[rr][5] += e * pv1.y;
      acc[rr][6] += e * pv1.z; acc[rr][7] += e * pv1.w;
    }
  }
  #pragma unroll
  for (int rr = 0; rr < 8; ++rr) {
    const int nloc = blockIdx.y * 32 + r0 + rr;
    uint4 pk;
    pk.x = pack2(acc[rr][0], acc[rr][1]);
    pk.y = pack2(acc[rr][2], acc[rr][3]);
    pk.z = pack2(acc[rr][4], acc[rr][5]);
    pk.w = pack2(acc[rr][6], acc[rr][7]);
    *reinterpret_cast<uint4*>(W + (long)nloc * WC + col0 + c8) = pk;
  }
}

// ---------------------------------------------------------------------------
// XH[b][n][0:64]=X, [64:128]=H  (fp32 -> fp16)
__global__ __launch_bounds__(256)
void k_build_xh(const float* __restrict__ X, const float* __restrict__ H,
                __half* __restrict__ XH) {
  const long i = (long)blockIdx.x * 256 + threadIdx.x;
  const long bn = i >> 5;
  const int  q  = (int)(i & 31);
  const float* src = (q < 16 ? X : H) + bn * 64 + (q & 15) * 4;
  const float4 v = *reinterpret_cast<const float4*>(src);
  ushort4 h;
  h.x = __half_as_ushort(__float2half(v.x));
  h.y = __half_as_ushort(__float2half(v.y));
  h.z = __half_as_ushort(__float2half(v.z));
  h.w = __half_as_ushort(__float2half(v.w));
  *reinterpret_cast<ushort4*>(XH + bn * CC_ + q * 4) = h;
}

// fp32 -> fp16 cast (fallback pools only)
__global__ __launch_bounds__(256)
void k_cast_f16(const float* __restrict__ src, __half* __restrict__ dst, int nquads) {
  const int i = blockIdx.x * 256 + threadIdx.x;
  if (i >= nquads) return;
  const float4 v = reinterpret_cast<const float4*>(src)[i];
  ushort4 h;
  h.x = __half_as_ushort(__float2half(v.x));
  h.y = __half_as_ushort(__float2half(v.y));
  h.z = __half_as_ushort(__float2half(v.z));
  h.w = __half_as_ushort(__float2half(v.w));
  *reinterpret_cast<ushort4*>(dst + i * 4) = h;
}

// bias[n][o] = sum_d E[n][d] * pool[d][o]
__global__ __launch_bounds__(256)
void k_bias(const float* __restrict__ E, const float* __restrict__ pool,
            float* __restrict__ bias, int O) {
  const int idx = blockIdx.x * 256 + threadIdx.x;
  const int n = idx / O, o = idx - n * O;
  float s = 0.f;
  #pragma unroll
  for (int d = 0; d < D_; ++d) s += E[n * D_ + d] * pool[d * O + o];
  bias[idx] = s;
}

// ---------------------------------------------------------------------------
// Shared staging of the data tile Ds[64b][128i] for support kc.
// kc=0: XH; kc=1: G1 (=A@XH); kc=2: 2*G2 - XH (Chebyshev, G2=A@G1).
static __device__ __forceinline__
void stage_data(int kc, const __half* XH, const __half* G1, const __half* G2,
                long base, int b, int seg, __half (*Ds)[136]) {
  if (kc < 2) {
    const uint4* s = reinterpret_cast<const uint4*>((kc ? G1 : XH) + base);
    uint4 v0 = s[0], v1 = s[1], v2 = s[2], v3 = s[3];
    uint4* d = reinterpret_cast<uint4*>(&Ds[b][seg * 32]);
    d[0] = v0; d[1] = v1; d[2] = v2; d[3] = v3;
  } else {
    const uint4* sg = reinterpret_cast<const uint4*>(G2 + base);
    const uint4* sx = reinterpret_cast<const uint4*>(XH + base);
    #pragma unroll
    for (int q = 0; q < 4; ++q) {
      uint4 g = sg[q], x = sx[q], r;
      const __half2* gh = reinterpret_cast<const __half2*>(&g);
      const __half2* xh = reinterpret_cast<const __half2*>(&x);
      __half2* rh = reinterpret_cast<__half2*>(&r);
      #pragma unroll
      for (int w = 0; w < 4; ++w) rh[w] = __hsub2(__hadd2(gh[w], gh[w]), xh[w]);
      reinterpret_cast<uint4*>(&Ds[b][seg * 32])[q] = r;
    }
  }
}

// ---------------------------------------------------------------------------
// Gate: node n = n0+blockIdx.x. ZR[64b x 128o] = sum_k XGk @ Wk + b, sigmoid;
// Z*H -> XH[...][64+o] (buffer becomes C), R -> Rbuf (fp16).
template <bool PRE>
__global__ __launch_bounds__(256)
void k_gate(const __half* __restrict__ XH, const __half* __restrict__ G1,
            const __half* __restrict__ G2, const __half* __restrict__ Wsrc,
            const float* __restrict__ E, const float* __restrict__ bg,
            const float* __restrict__ H, __half* __restrict__ XHw,
            __half* __restrict__ R, int n0) {
  const int bl = blockIdx.x, n = n0 + bl;
  const int t = threadIdx.x, lane = t & 63, wid = t >> 6;
  __shared__ __half Ws[128][136];
  __shared__ __half Ds[64][136];
  __shared__ float es[D_];
  if constexpr (!PRE) {
    if (t < D_) es[t] = E[n * D_ + t];
    __syncthreads();
  }
  f32x4 acc[4][2] = {};
  #pragma unroll
  for (int kc = 0; kc < 3; ++kc) {
    {
      const int b = t & 63, seg = t >> 6;
      stage_data(kc, XH, G1, G2, ((long)b * N_ + n) * CC_ + seg * 32, b, seg, Ds);
    }
    if constexpr (PRE) {
      const uint4* s4 = reinterpret_cast<const uint4*>(
          Wsrc + ((long)(bl * 3 + kc) * 128 + (t >> 1)) * 128 + (t & 1) * 64);
      uint4* dst = reinterpret_cast<uint4*>(&Ws[t >> 1][(t & 1) * 64]);
      #pragma unroll
      for (int q = 0; q < 8; ++q) dst[q] = s4[q];
    } else {
      const __half* pk = Wsrc + (long)kc * 128 * 128;
      for (int p = t; p < 64 * 128; p += 256) {
        const int o2 = p & 63, i = p >> 6;
        float w0 = 0.f, w1 = 0.f;
        #pragma unroll
        for (int d = 0; d < D_; ++d) {
          const __half2 h2 = *reinterpret_cast<const __half2*>(
              pk + (long)d * 3 * 128 * 128 + i * 128 + o2 * 2);
          const float e = es[d];
          w0 += e * __half2float(h2.x);
          w1 += e * __half2float(h2.y);
        }
        Ws[o2 * 2][i]     = __float2half(w0);
        Ws[o2 * 2 + 1][i] = __float2half(w1);
      }
    }
    __syncthreads();
    #pragma unroll
    for (int ks = 0; ks < 4; ++ks) {
      f16x8 a[4], bf[2];
      #pragma unroll
      for (int i = 0; i < 4; ++i)
        a[i] = *reinterpret_cast<const f16x8*>(&Ds[i * 16 + (lane & 15)][ks * 32 + (lane >> 4) * 8]);
      #pragma unroll
      for (int j = 0; j < 2; ++j)
        bf[j] = *reinterpret_cast<const f16x8*>(&Ws[wid * 32 + j * 16 + (lane & 15)][ks * 32 + (lane >> 4) * 8]);
      #pragma unroll
      for (int i = 0; i < 4; ++i)
        #pragma unroll
        for (int j = 0; j < 2; ++j)
          acc[i][j] = __builtin_amdgcn_mfma_f32_16x16x32_f16(a[i], bf[j], acc[i][j], 0, 0, 0);
    }
    __syncthreads();
  }
  const int cr = (lane >> 4) * 4, co = lane & 15;
  #pragma unroll
  for (int i = 0; i < 4; ++i)
    #pragma unroll
    for (int j = 0; j < 2; ++j) {
      const int o = wid * 32 + j * 16 + co;
      const float bv = bg[n * 128 + o];
      #pragma unroll
      for (int r = 0; r < 4; ++r) {
        const int b = i * 16 + cr + r;
        const float v = acc[i][j][r] + bv;
        const float s = 1.f / (1.f + __expf(-v));
        const long base = ((long)b * N_ + n) * CO_ + (o & 63);
        if (o < 64) {
          XHw[((long)b * N_ + n) * CC_ + 64 + o] = __float2half(s * H[base]);
        } else {
          R[base] = __float2half(s);
        }
      }
    }
}

// ---------------------------------------------------------------------------
// Update: HCpre[64b x 64o] = sum_k XGk @ Wk + b; out = R*H + (1-R)*tanh(.)
template <bool PRE>
__global__ __launch_bounds__(256)
void k_update(const __half* __restrict__ C, const __half* __restrict__ G1,
              const __half* __restrict__ G2, const __half* __restrict__ Wsrc,
              const float* __restrict__ E, const float* __restrict__ bu,
              const float* __restrict__ H, const __half* __restrict__ R,
              float* __restrict__ out, int n0) {
  const int bl = blockIdx.x, n = n0 + bl;
  const int t = threadIdx.x, lane = t & 63, wid = t >> 6;
  __shared__ __half Ws[64][136];
  __shared__ __half Ds[64][136];
  __shared__ float es[D_];
  if constexpr (!PRE) {
    if (t < D_) es[t] = E[n * D_ + t];
    __syncthreads();
  }
  f32x4 acc[4] = {};
  #pragma unroll
  for (int kc = 0; kc < 3; ++kc) {
    {
      const int b = t & 63, seg = t >> 6;
      stage_data(kc, C, G1, G2, ((long)b * N_ + n) * CC_ + seg * 32, b, seg, Ds);
    }
    if constexpr (PRE) {
      const uint4* s4 = reinterpret_cast<const uint4*>(
          Wsrc + ((long)(bl * 3 + kc) * 64 + (t >> 2)) * 128 + (t & 3) * 32);
      uint4* dst = reinterpret_cast<uint4*>(&Ws[t >> 2][(t & 3) * 32]);
      #pragma unroll
      for (int q = 0; q < 4; ++q) dst[q] = s4[q];
    } else {
      const __half* pk = Wsrc + (long)kc * 128 * 64;
      for (int p = t; p < 32 * 128; p += 256) {
        const int o2 = p & 31, i = p >> 5;
        float w0 = 0.f, w1 = 0.f;
        #pragma unroll
        for (int d = 0; d < D_; ++d) {
          const __half2 h2 = *reinterpret_cast<const __half2*>(
              pk + (long)d * 3 * 128 * 64 + i * 64 + o2 * 2);
          const float e = es[d];
          w0 += e * __half2float(h2.x);
          w1 += e * __half2float(h2.y);
        }
        Ws[o2 * 2][i]     = __float2half(w0);
        Ws[o2 * 2 + 1][i] = __float2half(w1);
      }
    }
    __syncthreads();
    #pragma unroll
    for (int ks = 0; ks < 4; ++ks) {
      f16x8 a[4], bf;
      #pragma unroll
      for (int i = 0; i < 4; ++i)
        a[i] = *reinterpret_cast<const f16x8*>(&Ds[i * 16 + (lane & 15)][ks * 32 + (lane >> 4) * 8]);
      bf = *reinterpret_cast<const f16x8*>(&Ws[wid * 16 + (lane & 15)][ks * 32 + (lane >> 4) * 8]);
      #pragma unroll
      for (int i = 0; i < 4; ++i)
        acc[i] = __builtin_amdgcn_mfma_f32_16x16x32_f16(a[i], bf, acc[i], 0, 0, 0);
    }
    __syncthreads();
  }
  const int cr = (lane >> 4) * 4, co = lane & 15;
  const int o = wid * 16 + co;
  const float bv = bu[n * 64 + o];
  #pragma unroll
  for (int i = 0; i < 4; ++i)
    #pragma unroll
    for (int r = 0; r < 4; ++r) {
      const int b = i * 16 + cr + r;
      const long idx = ((long)b * N_ + n) * CO_ + o;
      const float hc = tanhf(acc[i][r] + bv);
      const float rr = __half2float(R[idx]);
      out[idx] = rr * H[idx] + (1.f - rr) * hc;
    }
}

// ---------------------------------------------------------------------------
extern "C" void kernel_launch(void* const* d_in, const int* in_sizes, int n_in,
                              void* d_out, int out_size, void* d_ws, size_t ws_size,
                              hipStream_t stream) {
  const float* X  = (const float*)d_in[0];
  const float* E  = (const float*)d_in[1];
  const float* H  = (const float*)d_in[2];
  const float* gp = (const float*)d_in[3];  // [16][3][128][128]
  const float* gb = (const float*)d_in[4];  // [16][128]
  const float* up = (const float*)d_in[5];  // [16][3][128][64]
  const float* ub = (const float*)d_in[6];  // [16][64]
  float* out = (float*)d_out;

  size_t off = 0;
  auto alloc = [&](size_t bytes) {
    void* p = (char*)d_ws + off;
    off += (bytes + 255) & ~(size_t)255;
    return p;
  };
  __half* A16  = (__half*)alloc((size_t)N_ * N_ * 2);        // 8.4 MB
  __half* XH   = (__half*)alloc((size_t)B_ * N_ * CC_ * 2);  // 33.6 MB (becomes C)
  __half* G1   = (__half*)alloc((size_t)B_ * N_ * CC_ * 2);  // 33.6 MB
  __half* G2   = (__half*)alloc((size_t)B_ * N_ * CC_ * 2);  // 33.6 MB
  __half* Rb   = (__half*)alloc((size_t)B_ * N_ * CO_ * 2);  // 16.8 MB
  float*  bg   = (float*)alloc((size_t)N_ * 128 * 4);
  float*  bu   = (float*)alloc((size_t)N_ * 64 * 4);

  __half* Wbuf = (__half*)((char*)d_ws + off);
  const size_t rem = (ws_size > off) ? ws_size - off : 0;
  long cgl = (long)(rem / 98304) & ~31L;  // gate: 3*128*128*2 B per node
  long cul = (long)(rem / 49152) & ~31L;  // update: 3*64*128*2 B per node
  const int cg = (int)(cgl > N_ ? N_ : cgl);
  const int cu = (int)(cul > N_ ? N_ : cul);
  const bool pre = cg >= 32;

  const long sXH = (long)N_ * CC_;

  k_bias<<<1024, 256, 0, stream>>>(E, gb, bg, 128);
  k_bias<<<512, 256, 0, stream>>>(E, ub, bu, 64);
  k_softmaxA<<<N_, 256, 0, stream>>>(E, A16);
  k_build_xh<<<16384, 256, 0, stream>>>(X, H, XH);

  // gate propagation: G1 = A@XH, G2 = A@G1 (S2@XH = 2*G2 - XH in staging)
  k_gemm<<<dim3(16, 1, B_), 256, 0, stream>>>(A16, XH, G1, N_, N_, CC_, CC_, sXH, sXH);
  k_gemm<<<dim3(16, 1, B_), 256, 0, stream>>>(A16, G1, G2, N_, N_, CC_, CC_, sXH, sXH);

  __half* pg = nullptr;
  __half* pu = nullptr;
  if (pre) {
    for (int n0 = 0; n0 < N_; n0 += cg) {
      const int cnt = (N_ - n0 < cg) ? N_ - n0 : cg;
      k_wpre<128><<<dim3(96, cnt / 32), 256, 0, stream>>>(gp, E, Wbuf, n0);
      k_gate<true><<<cnt, 256, 0, stream>>>(XH, G1, G2, Wbuf, E, bg, H, XH, Rb, n0);
    }
  } else {
    pg = (__half*)alloc((size_t)D_ * 3 * 128 * 128 * 2);
    pu = (__half*)alloc((size_t)D_ * 3 * 128 * 64 * 2);
    k_cast_f16<<<768, 256, 0, stream>>>(gp, pg, 196608);
    k_cast_f16<<<384, 256, 0, stream>>>(up, pu, 98304);
    k_gate<false><<<N_, 256, 0, stream>>>(XH, G1, G2, pg, E, bg, H, XH, Rb, 0);
  }

  // update propagation (XH now holds C = [X, Z*H])
  k_gemm<<<dim3(16, 1, B_), 256, 0, stream>>>(A16, XH, G1, N_, N_, CC_, CC_, sXH, sXH);
  k_gemm<<<dim3(16, 1, B_), 256, 0, stream>>>(A16, G1, G2, N_, N_, CC_, CC_, sXH, sXH);

  if (pre) {
    for (int n0 = 0; n0 < N_; n0 += cu) {
      const int cnt = (N_ - n0 < cu) ? N_ - n0 : cu;
      k_wpre<64><<<dim3(48, cnt / 32), 256, 0, stream>>>(up, E, Wbuf, n0);
      k_update<true><<<cnt, 256, 0, stream>>>(XH, G1, G2, Wbuf, E, bu, H, Rb, out, n0);
    }
  } else {
    k_update<false><<<N_, 256, 0, stream>>>(XH, G1, G2, pu, E, bu, H, Rb, out, 0);
  }
}

// Round 4
// 910.345 us; speedup vs baseline: 1.5576x; 1.1135x over previous
//
#include <hip/hip_runtime.h>
#include <hip/hip_fp16.h>

// AGCRN cell on MI355X. fp16 MFMA (16x16x32) + fp32 accum; fp32 nonlinearities.
// Round 4: propagation GEMM rewritten m97-style: BK=64, global_load_lds(16B)
// for A with granule-XOR-swizzled source (bank-conflict-free b128 frag reads),
// B staged via coalesced uint4 + register 4x8 transpose + ds_write_b64 into the
// same XOR layout (replaces the 16-scalar-u16 gather that made VALUBusy 31%).
// Buffers/flow identical to round 3 (pre-W chunked path).

#define B_  64
#define N_  2048
#define D_  16
#define CO_ 64
#define CC_ 128   // concat channels (in+out)

typedef _Float16 f16x8 __attribute__((ext_vector_type(8)));
typedef float    f32x4 __attribute__((ext_vector_type(4)));
typedef unsigned short u16x8 __attribute__((ext_vector_type(8)));

#define GLOAD_LDS16(g, l)                                          \
  __builtin_amdgcn_global_load_lds(                                \
      (const __attribute__((address_space(1))) unsigned int*)(g),  \
      (__attribute__((address_space(3))) unsigned int*)(l), 16, 0, 0)

static __device__ __forceinline__ uint pack2(float a, float b) {
  return (uint)__half_as_ushort(__float2half(a)) |
         ((uint)__half_as_ushort(__float2half(b)) << 16);
}

// ---------------------------------------------------------------------------
// A = softmax(relu(E E^T)) row-wise, stored fp16. One block per row.
__global__ __launch_bounds__(256)
void k_softmaxA(const float* __restrict__ E, __half* __restrict__ A) {
  const int n = blockIdx.x, t = threadIdx.x;
  __shared__ float row[N_];
  __shared__ float red[4];
  const float4* en4 = reinterpret_cast<const float4*>(E + n * D_);
  const float4 e0 = en4[0], e1 = en4[1], e2 = en4[2], e3 = en4[3];
  float lmax = 0.f;  // relu => scores >= 0
  for (int m = t; m < N_; m += 256) {
    const float4* em4 = reinterpret_cast<const float4*>(E + m * D_);
    const float4 f0 = em4[0], f1 = em4[1], f2 = em4[2], f3 = em4[3];
    float d = e0.x*f0.x + e0.y*f0.y + e0.z*f0.z + e0.w*f0.w
            + e1.x*f1.x + e1.y*f1.y + e1.z*f1.z + e1.w*f1.w
            + e2.x*f2.x + e2.y*f2.y + e2.z*f2.z + e2.w*f2.w
            + e3.x*f3.x + e3.y*f3.y + e3.z*f3.z + e3.w*f3.w;
    d = fmaxf(d, 0.f);
    row[m] = d;
    lmax = fmaxf(lmax, d);
  }
  #pragma unroll
  for (int off = 32; off > 0; off >>= 1) lmax = fmaxf(lmax, __shfl_down(lmax, off));
  __syncthreads();
  if ((t & 63) == 0) red[t >> 6] = lmax;
  __syncthreads();
  const float gmax = fmaxf(fmaxf(red[0], red[1]), fmaxf(red[2], red[3]));
  float lsum = 0.f;
  for (int m = t; m < N_; m += 256) {
    float v = __expf(row[m] - gmax);
    row[m] = v;
    lsum += v;
  }
  #pragma unroll
  for (int off = 32; off > 0; off >>= 1) lsum += __shfl_down(lsum, off);
  __syncthreads();
  if ((t & 63) == 0) red[t >> 6] = lsum;
  __syncthreads();
  const float rinv = 1.f / (red[0] + red[1] + red[2] + red[3]);
  for (int m = t; m < N_; m += 256)
    A[(long)n * N_ + m] = __float2half(row[m] * rinv);
}

// ---------------------------------------------------------------------------
// Propagation GEMM: C[b] = A @ B[b].  A:[2048x2048] f16 row-major,
// B:[2048x128] per batch (stride sB), C likewise. Tile 128x128, BK=64,
// 4 waves. LDS granule-swizzled: element (row, k) of a [128][64] tile lives at
// halves row*64 + ((k>>3 ^ swz(row-or-col)) * 8) + (k&7).
//   A side: swz = row & 7     (matches gload_lds pre-swizzled source)
//   B side: swz = ((j>>3)&7) ^ (j&7)
__global__ __launch_bounds__(256)
void k_gemm2(const __half* __restrict__ Ag, const __half* __restrict__ Bg,
             __half* __restrict__ Cg, long sB, long sC) {
  const int m0 = blockIdx.x * 128;
  Bg += (long)blockIdx.z * sB;
  Cg += (long)blockIdx.z * sC;
  __shared__ __half As[128 * 64];
  __shared__ __half Bs[128 * 64];
  const int t = threadIdx.x, lane = t & 63, wid = t >> 6;
  const int wm = (wid & 1) * 64, wn = (wid >> 1) * 64;
  const int l15 = lane & 15, lq = lane >> 4;
  f32x4 acc[4][4] = {};

  // A staging (gload_lds): each inst covers 8 rows x 64k (1KB); lane supplies
  // the element that belongs at LDS offset base + lane*16B.
  const int arow_l = lane >> 3;        // row within the 8-row group
  const int aslot  = lane & 7;         // granule slot this lane fills
  const int agran  = aslot ^ arow_l;   // logical k-granule fetched

  // B staging: thread owns a 4k x 8c micro-tile.
  const int jt = t & 15, kg = t >> 4;
  const int c0 = jt * 8, k0 = kg * 4;
  const int g4 = kg >> 1, khalf = kg & 1;

  for (int kt = 0; kt < N_; kt += 64) {
    // ---- stage A: 4 x global_load_lds_dwordx4 per wave
    #pragma unroll
    for (int i = 0; i < 4; ++i) {
      const int row8 = (wid * 4 + i) * 8;
      const __half* src = Ag + (long)(m0 + row8 + arow_l) * N_ + kt + agran * 8;
      GLOAD_LDS16(src, As + row8 * 64);
    }
    // ---- stage B: 4 coalesced uint4 loads, register transpose, 8 b64 writes
    {
      u16x8 bv[4];
      #pragma unroll
      for (int r = 0; r < 4; ++r)
        bv[r] = *reinterpret_cast<const u16x8*>(Bg + (long)(kt + k0 + r) * CC_ + c0);
      #pragma unroll
      for (int jc = 0; jc < 8; ++jc) {
        const int j = c0 + jc;
        const int s = ((j >> 3) & 7) ^ (j & 7);
        ushort4 w;
        w.x = bv[0][jc]; w.y = bv[1][jc]; w.z = bv[2][jc]; w.w = bv[3][jc];
        *reinterpret_cast<ushort4*>(Bs + j * 64 + ((g4 ^ s) << 3) + (khalf << 2)) = w;
      }
    }
    __syncthreads();
    // ---- compute: 2 k-halves x (4m x 4n) MFMAs
    #pragma unroll
    for (int kh = 0; kh < 2; ++kh) {
      const int gr = kh * 4 + lq;  // k-granule of this lane's fragment
      f16x8 af[4], bf[4];
      #pragma unroll
      for (int i = 0; i < 4; ++i) {
        const int row = wm + i * 16 + l15;
        af[i] = *reinterpret_cast<const f16x8*>(As + row * 64 + ((gr ^ (row & 7)) << 3));
      }
      #pragma unroll
      for (int j = 0; j < 4; ++j) {
        const int col = wn + j * 16 + l15;
        const int s = ((col >> 3) & 7) ^ (col & 7);
        bf[j] = *reinterpret_cast<const f16x8*>(Bs + col * 64 + ((gr ^ s) << 3));
      }
      #pragma unroll
      for (int i = 0; i < 4; ++i)
        #pragma unroll
        for (int j = 0; j < 4; ++j)
          acc[i][j] = __builtin_amdgcn_mfma_f32_16x16x32_f16(af[i], bf[j], acc[i][j], 0, 0, 0);
    }
    __syncthreads();
  }
  // epilogue: D[row=(lane>>4)*4+r, col=lane&15]
  const int cr = lq * 4, ccol = l15;
  #pragma unroll
  for (int i = 0; i < 4; ++i)
    #pragma unroll
    for (int j = 0; j < 4; ++j) {
      const int grow = m0 + wm + i * 16 + cr;
      const int gcol = wn + j * 16 + ccol;
      #pragma unroll
      for (int r = 0; r < 4; ++r)
        Cg[(long)(grow + r) * CC_ + gcol] = __float2half(acc[i][j][r]);
    }
}

// ---------------------------------------------------------------------------
// W precompute for a node chunk: W[nloc][kc][o][i] = sum_d E[n0+nloc,d]*pool[d][kc][i][o].
template <int OSZ>
__global__ __launch_bounds__(256)
void k_wpre(const float* __restrict__ pool, const float* __restrict__ E,
            __half* __restrict__ W, int n0) {
  const int WC = 3 * OSZ * 128;
  const int col0 = blockIdx.x * 512;
  const int kc = col0 / (OSZ * 128);
  const int o0 = (col0 - kc * OSZ * 128) >> 7;
  const int t = threadIdx.x;
  __shared__ float PoolS[16 * 768];
  __shared__ float Es[32][16];
  for (int p = t; p < 512; p += 256)
    Es[p >> 4][p & 15] = E[(n0 + blockIdx.y * 32 + (p >> 4)) * 16 + (p & 15)];
  for (int p = t; p < 16 * 512; p += 256) {
    const int d = p >> 9, jl = p & 511;
    const int o = o0 + (jl >> 7), i = jl & 127;
    PoolS[d * 768 + (jl >> 3) * 12 + (jl & 7)] =
        pool[((long)(d * 3 + kc) * 128 + i) * OSZ + o];
  }
  __syncthreads();
  const int c8 = (t & 63) * 8;
  const int r0 = (t >> 6) * 8;
  const int cbase = (t & 63) * 12;
  float acc[8][8] = {};
  #pragma unroll
  for (int d = 0; d < 16; ++d) {
    const float4 pv0 = *reinterpret_cast<const float4*>(&PoolS[d * 768 + cbase]);
    const float4 pv1 = *reinterpret_cast<const float4*>(&PoolS[d * 768 + cbase + 4]);
    #pragma unroll
    for (int rr = 0; rr < 8; ++rr) {
      const float e = Es[r0 + rr][d];
      acc[rr][0] += e * pv0.x; acc[rr][1] += e * pv0.y;
      acc[rr][2] += e * pv0.z; acc[rr][3] += e * pv0.w;
      acc[rr][4] += e * pv1.x; acc[rr][5] += e * pv1.y;
      acc[rr][6] += e * pv1.z; acc[rr][7] += e * pv1.w;
    }
  }
  #pragma unroll
  for (int rr = 0; rr < 8; ++rr) {
    const int nloc = blockIdx.y * 32 + r0 + rr;
    uint4 pk;
    pk.x = pack2(acc[rr][0], acc[rr][1]);
    pk.y = pack2(acc[rr][2], acc[rr][3]);
    pk.z = pack2(acc[rr][4], acc[rr][5]);
    pk.w = pack2(acc[rr][6], acc[rr][7]);
    *reinterpret_cast<uint4*>(W + (long)nloc * WC + col0 + c8) = pk;
  }
}

// ---------------------------------------------------------------------------
// XH[b][n][0:64]=X, [64:128]=H  (fp32 -> fp16)
__global__ __launch_bounds__(256)
void k_build_xh(const float* __restrict__ X, const float* __restrict__ H,
                __half* __restrict__ XH) {
  const long i = (long)blockIdx.x * 256 + threadIdx.x;
  const long bn = i >> 5;
  const int  q  = (int)(i & 31);
  const float* src = (q < 16 ? X : H) + bn * 64 + (q & 15) * 4;
  const float4 v = *reinterpret_cast<const float4*>(src);
  ushort4 h;
  h.x = __half_as_ushort(__float2half(v.x));
  h.y = __half_as_ushort(__float2half(v.y));
  h.z = __half_as_ushort(__float2half(v.z));
  h.w = __half_as_ushort(__float2half(v.w));
  *reinterpret_cast<ushort4*>(XH + bn * CC_ + q * 4) = h;
}

// fp32 -> fp16 cast (fallback pools only)
__global__ __launch_bounds__(256)
void k_cast_f16(const float* __restrict__ src, __half* __restrict__ dst, int nquads) {
  const int i = blockIdx.x * 256 + threadIdx.x;
  if (i >= nquads) return;
  const float4 v = reinterpret_cast<const float4*>(src)[i];
  ushort4 h;
  h.x = __half_as_ushort(__float2half(v.x));
  h.y = __half_as_ushort(__float2half(v.y));
  h.z = __half_as_ushort(__float2half(v.z));
  h.w = __half_as_ushort(__float2half(v.w));
  *reinterpret_cast<ushort4*>(dst + i * 4) = h;
}

// bias[n][o] = sum_d E[n][d] * pool[d][o]
__global__ __launch_bounds__(256)
void k_bias(const float* __restrict__ E, const float* __restrict__ pool,
            float* __restrict__ bias, int O) {
  const int idx = blockIdx.x * 256 + threadIdx.x;
  const int n = idx / O, o = idx - n * O;
  float s = 0.f;
  #pragma unroll
  for (int d = 0; d < D_; ++d) s += E[n * D_ + d] * pool[d * O + o];
  bias[idx] = s;
}

// ---------------------------------------------------------------------------
// Shared staging of the data tile Ds[64b][128i] for support kc.
// kc=0: XH; kc=1: G1 (=A@XH); kc=2: 2*G2 - XH (Chebyshev, G2=A@G1).
static __device__ __forceinline__
void stage_data(int kc, const __half* XH, const __half* G1, const __half* G2,
                long base, int b, int seg, __half (*Ds)[136]) {
  if (kc < 2) {
    const uint4* s = reinterpret_cast<const uint4*>((kc ? G1 : XH) + base);
    uint4 v0 = s[0], v1 = s[1], v2 = s[2], v3 = s[3];
    uint4* d = reinterpret_cast<uint4*>(&Ds[b][seg * 32]);
    d[0] = v0; d[1] = v1; d[2] = v2; d[3] = v3;
  } else {
    const uint4* sg = reinterpret_cast<const uint4*>(G2 + base);
    const uint4* sx = reinterpret_cast<const uint4*>(XH + base);
    #pragma unroll
    for (int q = 0; q < 4; ++q) {
      uint4 g = sg[q], x = sx[q], r;
      const __half2* gh = reinterpret_cast<const __half2*>(&g);
      const __half2* xh = reinterpret_cast<const __half2*>(&x);
      __half2* rh = reinterpret_cast<__half2*>(&r);
      #pragma unroll
      for (int w = 0; w < 4; ++w) rh[w] = __hsub2(__hadd2(gh[w], gh[w]), xh[w]);
      reinterpret_cast<uint4*>(&Ds[b][seg * 32])[q] = r;
    }
  }
}

// ---------------------------------------------------------------------------
// Gate: node n = n0+blockIdx.x. ZR[64b x 128o] = sum_k XGk @ Wk + b, sigmoid;
// Z*H -> XH[...][64+o] (buffer becomes C), R -> Rbuf (fp16).
template <bool PRE>
__global__ __launch_bounds__(256)
void k_gate(const __half* __restrict__ XH, const __half* __restrict__ G1,
            const __half* __restrict__ G2, const __half* __restrict__ Wsrc,
            const float* __restrict__ E, const float* __restrict__ bg,
            const float* __restrict__ H, __half* __restrict__ XHw,
            __half* __restrict__ R, int n0) {
  const int bl = blockIdx.x, n = n0 + bl;
  const int t = threadIdx.x, lane = t & 63, wid = t >> 6;
  __shared__ __half Ws[128][136];
  __shared__ __half Ds[64][136];
  __shared__ float es[D_];
  if constexpr (!PRE) {
    if (t < D_) es[t] = E[n * D_ + t];
    __syncthreads();
  }
  f32x4 acc[4][2] = {};
  #pragma unroll
  for (int kc = 0; kc < 3; ++kc) {
    {
      const int b = t & 63, seg = t >> 6;
      stage_data(kc, XH, G1, G2, ((long)b * N_ + n) * CC_ + seg * 32, b, seg, Ds);
    }
    if constexpr (PRE) {
      const uint4* s4 = reinterpret_cast<const uint4*>(
          Wsrc + ((long)(bl * 3 + kc) * 128 + (t >> 1)) * 128 + (t & 1) * 64);
      uint4* dst = reinterpret_cast<uint4*>(&Ws[t >> 1][(t & 1) * 64]);
      #pragma unroll
      for (int q = 0; q < 8; ++q) dst[q] = s4[q];
    } else {
      const __half* pk = Wsrc + (long)kc * 128 * 128;
      for (int p = t; p < 64 * 128; p += 256) {
        const int o2 = p & 63, i = p >> 6;
        float w0 = 0.f, w1 = 0.f;
        #pragma unroll
        for (int d = 0; d < D_; ++d) {
          const __half2 h2 = *reinterpret_cast<const __half2*>(
              pk + (long)d * 3 * 128 * 128 + i * 128 + o2 * 2);
          const float e = es[d];
          w0 += e * __half2float(h2.x);
          w1 += e * __half2float(h2.y);
        }
        Ws[o2 * 2][i]     = __float2half(w0);
        Ws[o2 * 2 + 1][i] = __float2half(w1);
      }
    }
    __syncthreads();
    #pragma unroll
    for (int ks = 0; ks < 4; ++ks) {
      f16x8 a[4], bf[2];
      #pragma unroll
      for (int i = 0; i < 4; ++i)
        a[i] = *reinterpret_cast<const f16x8*>(&Ds[i * 16 + (lane & 15)][ks * 32 + (lane >> 4) * 8]);
      #pragma unroll
      for (int j = 0; j < 2; ++j)
        bf[j] = *reinterpret_cast<const f16x8*>(&Ws[wid * 32 + j * 16 + (lane & 15)][ks * 32 + (lane >> 4) * 8]);
      #pragma unroll
      for (int i = 0; i < 4; ++i)
        #pragma unroll
        for (int j = 0; j < 2; ++j)
          acc[i][j] = __builtin_amdgcn_mfma_f32_16x16x32_f16(a[i], bf[j], acc[i][j], 0, 0, 0);
    }
    __syncthreads();
  }
  const int cr = (lane >> 4) * 4, co = lane & 15;
  #pragma unroll
  for (int i = 0; i < 4; ++i)
    #pragma unroll
    for (int j = 0; j < 2; ++j) {
      const int o = wid * 32 + j * 16 + co;
      const float bv = bg[n * 128 + o];
      #pragma unroll
      for (int r = 0; r < 4; ++r) {
        const int b = i * 16 + cr + r;
        const float v = acc[i][j][r] + bv;
        const float s = 1.f / (1.f + __expf(-v));
        const long base = ((long)b * N_ + n) * CO_ + (o & 63);
        if (o < 64) {
          XHw[((long)b * N_ + n) * CC_ + 64 + o] = __float2half(s * H[base]);
        } else {
          R[base] = __float2half(s);
        }
      }
    }
}

// ---------------------------------------------------------------------------
// Update: HCpre[64b x 64o] = sum_k XGk @ Wk + b; out = R*H + (1-R)*tanh(.)
template <bool PRE>
__global__ __launch_bounds__(256)
void k_update(const __half* __restrict__ C, const __half* __restrict__ G1,
              const __half* __restrict__ G2, const __half* __restrict__ Wsrc,
              const float* __restrict__ E, const float* __restrict__ bu,
              const float* __restrict__ H, const __half* __restrict__ R,
              float* __restrict__ out, int n0) {
  const int bl = blockIdx.x, n = n0 + bl;
  const int t = threadIdx.x, lane = t & 63, wid = t >> 6;
  __shared__ __half Ws[64][136];
  __shared__ __half Ds[64][136];
  __shared__ float es[D_];
  if constexpr (!PRE) {
    if (t < D_) es[t] = E[n * D_ + t];
    __syncthreads();
  }
  f32x4 acc[4] = {};
  #pragma unroll
  for (int kc = 0; kc < 3; ++kc) {
    {
      const int b = t & 63, seg = t >> 6;
      stage_data(kc, C, G1, G2, ((long)b * N_ + n) * CC_ + seg * 32, b, seg, Ds);
    }
    if constexpr (PRE) {
      const uint4* s4 = reinterpret_cast<const uint4*>(
          Wsrc + ((long)(bl * 3 + kc) * 64 + (t >> 2)) * 128 + (t & 3) * 32);
      uint4* dst = reinterpret_cast<uint4*>(&Ws[t >> 2][(t & 3) * 32]);
      #pragma unroll
      for (int q = 0; q < 4; ++q) dst[q] = s4[q];
    } else {
      const __half* pk = Wsrc + (long)kc * 128 * 64;
      for (int p = t; p < 32 * 128; p += 256) {
        const int o2 = p & 31, i = p >> 5;
        float w0 = 0.f, w1 = 0.f;
        #pragma unroll
        for (int d = 0; d < D_; ++d) {
          const __half2 h2 = *reinterpret_cast<const __half2*>(
              pk + (long)d * 3 * 128 * 64 + i * 64 + o2 * 2);
          const float e = es[d];
          w0 += e * __half2float(h2.x);
          w1 += e * __half2float(h2.y);
        }
        Ws[o2 * 2][i]     = __float2half(w0);
        Ws[o2 * 2 + 1][i] = __float2half(w1);
      }
    }
    __syncthreads();
    #pragma unroll
    for (int ks = 0; ks < 4; ++ks) {
      f16x8 a[4], bf;
      #pragma unroll
      for (int i = 0; i < 4; ++i)
        a[i] = *reinterpret_cast<const f16x8*>(&Ds[i * 16 + (lane & 15)][ks * 32 + (lane >> 4) * 8]);
      bf = *reinterpret_cast<const f16x8*>(&Ws[wid * 16 + (lane & 15)][ks * 32 + (lane >> 4) * 8]);
      #pragma unroll
      for (int i = 0; i < 4; ++i)
        acc[i] = __builtin_amdgcn_mfma_f32_16x16x32_f16(a[i], bf, acc[i], 0, 0, 0);
    }
    __syncthreads();
  }
  const int cr = (lane >> 4) * 4, co = lane & 15;
  const int o = wid * 16 + co;
  const float bv = bu[n * 64 + o];
  #pragma unroll
  for (int i = 0; i < 4; ++i)
    #pragma unroll
    for (int r = 0; r < 4; ++r) {
      const int b = i * 16 + cr + r;
      const long idx = ((long)b * N_ + n) * CO_ + o;
      const float hc = tanhf(acc[i][r] + bv);
      const float rr = __half2float(R[idx]);
      out[idx] = rr * H[idx] + (1.f - rr) * hc;
    }
}

// ---------------------------------------------------------------------------
extern "C" void kernel_launch(void* const* d_in, const int* in_sizes, int n_in,
                              void* d_out, int out_size, void* d_ws, size_t ws_size,
                              hipStream_t stream) {
  const float* X  = (const float*)d_in[0];
  const float* E  = (const float*)d_in[1];
  const float* H  = (const float*)d_in[2];
  const float* gp = (const float*)d_in[3];  // [16][3][128][128]
  const float* gb = (const float*)d_in[4];  // [16][128]
  const float* up = (const float*)d_in[5];  // [16][3][128][64]
  const float* ub = (const float*)d_in[6];  // [16][64]
  float* out = (float*)d_out;

  size_t off = 0;
  auto alloc = [&](size_t bytes) {
    void* p = (char*)d_ws + off;
    off += (bytes + 255) & ~(size_t)255;
    return p;
  };
  __half* A16  = (__half*)alloc((size_t)N_ * N_ * 2);        // 8.4 MB
  __half* XH   = (__half*)alloc((size_t)B_ * N_ * CC_ * 2);  // 33.6 MB (becomes C)
  __half* G1   = (__half*)alloc((size_t)B_ * N_ * CC_ * 2);  // 33.6 MB
  __half* G2   = (__half*)alloc((size_t)B_ * N_ * CC_ * 2);  // 33.6 MB
  __half* Rb   = (__half*)alloc((size_t)B_ * N_ * CO_ * 2);  // 16.8 MB
  float*  bg   = (float*)alloc((size_t)N_ * 128 * 4);
  float*  bu   = (float*)alloc((size_t)N_ * 64 * 4);

  __half* Wbuf = (__half*)((char*)d_ws + off);
  const size_t rem = (ws_size > off) ? ws_size - off : 0;
  long cgl = (long)(rem / 98304) & ~31L;  // gate: 3*128*128*2 B per node
  long cul = (long)(rem / 49152) & ~31L;  // update: 3*64*128*2 B per node
  const int cg = (int)(cgl > N_ ? N_ : cgl);
  const int cu = (int)(cul > N_ ? N_ : cul);
  const bool pre = cg >= 32;

  const long sXH = (long)N_ * CC_;

  k_bias<<<1024, 256, 0, stream>>>(E, gb, bg, 128);
  k_bias<<<512, 256, 0, stream>>>(E, ub, bu, 64);
  k_softmaxA<<<N_, 256, 0, stream>>>(E, A16);
  k_build_xh<<<16384, 256, 0, stream>>>(X, H, XH);

  // gate propagation: G1 = A@XH, G2 = A@G1 (S2@XH = 2*G2 - XH in staging)
  k_gemm2<<<dim3(16, 1, B_), 256, 0, stream>>>(A16, XH, G1, sXH, sXH);
  k_gemm2<<<dim3(16, 1, B_), 256, 0, stream>>>(A16, G1, G2, sXH, sXH);

  __half* pg = nullptr;
  __half* pu = nullptr;
  if (pre) {
    for (int n0 = 0; n0 < N_; n0 += cg) {
      const int cnt = (N_ - n0 < cg) ? N_ - n0 : cg;
      k_wpre<128><<<dim3(96, cnt / 32), 256, 0, stream>>>(gp, E, Wbuf, n0);
      k_gate<true><<<cnt, 256, 0, stream>>>(XH, G1, G2, Wbuf, E, bg, H, XH, Rb, n0);
    }
  } else {
    pg = (__half*)alloc((size_t)D_ * 3 * 128 * 128 * 2);
    pu = (__half*)alloc((size_t)D_ * 3 * 128 * 64 * 2);
    k_cast_f16<<<768, 256, 0, stream>>>(gp, pg, 196608);
    k_cast_f16<<<384, 256, 0, stream>>>(up, pu, 98304);
    k_gate<false><<<N_, 256, 0, stream>>>(XH, G1, G2, pg, E, bg, H, XH, Rb, 0);
  }

  // update propagation (XH now holds C = [X, Z*H])
  k_gemm2<<<dim3(16, 1, B_), 256, 0, stream>>>(A16, XH, G1, sXH, sXH);
  k_gemm2<<<dim3(16, 1, B_), 256, 0, stream>>>(A16, G1, G2, sXH, sXH);

  if (pre) {
    for (int n0 = 0; n0 < N_; n0 += cu) {
      const int cnt = (N_ - n0 < cu) ? N_ - n0 : cu;
      k_wpre<64><<<dim3(48, cnt / 32), 256, 0, stream>>>(up, E, Wbuf, n0);
      k_update<true><<<cnt, 256, 0, stream>>>(XH, G1, G2, Wbuf, E, bu, H, Rb, out, n0);
    }
  } else {
    k_update<false><<<N_, 256, 0, stream>>>(XH, G1, G2, pu, E, bu, H, Rb, out, 0);
  }
}

// Round 5
// 909.261 us; speedup vs baseline: 1.5595x; 1.0012x over previous
//
#include <hip/hip_runtime.h>
#include <hip/hip_fp16.h>

// AGCRN cell on MI355X. fp16 MFMA (16x16x32) + fp32 accum; fp32 nonlinearities.
// Round 5: (a) k_gate/k_update: drop the Ws LDS staging entirely -- W fragments
// have zero reuse (one wave, one frag) so they are read straight from global as
// 16B b128 frag loads (LDS 52.7->17.4KB, fewer insts, more blocks/CU);
// (b) k_gemm2: bijective chunked XCD swizzle so each XCD keeps 8 batches'
// B-panels (4MB) hot in its private L2.

#define B_  64
#define N_  2048
#define D_  16
#define CO_ 64
#define CC_ 128   // concat channels (in+out)

typedef _Float16 f16x8 __attribute__((ext_vector_type(8)));
typedef float    f32x4 __attribute__((ext_vector_type(4)));
typedef unsigned short u16x8 __attribute__((ext_vector_type(8)));

#define GLOAD_LDS16(g, l)                                          \
  __builtin_amdgcn_global_load_lds(                                \
      (const __attribute__((address_space(1))) unsigned int*)(g),  \
      (__attribute__((address_space(3))) unsigned int*)(l), 16, 0, 0)

static __device__ __forceinline__ uint pack2(float a, float b) {
  return (uint)__half_as_ushort(__float2half(a)) |
         ((uint)__half_as_ushort(__float2half(b)) << 16);
}

// ---------------------------------------------------------------------------
// A = softmax(relu(E E^T)) row-wise, stored fp16. One block per row.
__global__ __launch_bounds__(256)
void k_softmaxA(const float* __restrict__ E, __half* __restrict__ A) {
  const int n = blockIdx.x, t = threadIdx.x;
  __shared__ float row[N_];
  __shared__ float red[4];
  const float4* en4 = reinterpret_cast<const float4*>(E + n * D_);
  const float4 e0 = en4[0], e1 = en4[1], e2 = en4[2], e3 = en4[3];
  float lmax = 0.f;  // relu => scores >= 0
  for (int m = t; m < N_; m += 256) {
    const float4* em4 = reinterpret_cast<const float4*>(E + m * D_);
    const float4 f0 = em4[0], f1 = em4[1], f2 = em4[2], f3 = em4[3];
    float d = e0.x*f0.x + e0.y*f0.y + e0.z*f0.z + e0.w*f0.w
            + e1.x*f1.x + e1.y*f1.y + e1.z*f1.z + e1.w*f1.w
            + e2.x*f2.x + e2.y*f2.y + e2.z*f2.z + e2.w*f2.w
            + e3.x*f3.x + e3.y*f3.y + e3.z*f3.z + e3.w*f3.w;
    d = fmaxf(d, 0.f);
    row[m] = d;
    lmax = fmaxf(lmax, d);
  }
  #pragma unroll
  for (int off = 32; off > 0; off >>= 1) lmax = fmaxf(lmax, __shfl_down(lmax, off));
  __syncthreads();
  if ((t & 63) == 0) red[t >> 6] = lmax;
  __syncthreads();
  const float gmax = fmaxf(fmaxf(red[0], red[1]), fmaxf(red[2], red[3]));
  float lsum = 0.f;
  for (int m = t; m < N_; m += 256) {
    float v = __expf(row[m] - gmax);
    row[m] = v;
    lsum += v;
  }
  #pragma unroll
  for (int off = 32; off > 0; off >>= 1) lsum += __shfl_down(lsum, off);
  __syncthreads();
  if ((t & 63) == 0) red[t >> 6] = lsum;
  __syncthreads();
  const float rinv = 1.f / (red[0] + red[1] + red[2] + red[3]);
  for (int m = t; m < N_; m += 256)
    A[(long)n * N_ + m] = __float2half(row[m] * rinv);
}

// ---------------------------------------------------------------------------
// Propagation GEMM: C[b] = A @ B[b].  Tile 128(m) x 128(n=all), BK=64, 4 waves.
// XCD swizzle: hardware linear id j -> logical tile (j&7)*128 + (j>>3), so
// XCD k owns batches [8k, 8k+8) and their B-panels stay hot in its L2.
__global__ __launch_bounds__(256)
void k_gemm2(const __half* __restrict__ Ag, const __half* __restrict__ Bg,
             __half* __restrict__ Cg, long sB, long sC) {
  const int j0 = blockIdx.z * 16 + blockIdx.x;   // hardware linear id (x fastest)
  const int orig = (j0 & 7) * 128 + (j0 >> 3);   // bijective for 1024 blocks
  const int m0 = (orig & 15) * 128;
  const int zb = orig >> 4;
  Bg += (long)zb * sB;
  Cg += (long)zb * sC;
  __shared__ __half As[128 * 64];
  __shared__ __half Bs[128 * 64];
  const int t = threadIdx.x, lane = t & 63, wid = t >> 6;
  const int wm = (wid & 1) * 64, wn = (wid >> 1) * 64;
  const int l15 = lane & 15, lq = lane >> 4;
  f32x4 acc[4][4] = {};

  const int arow_l = lane >> 3;        // row within the 8-row group
  const int aslot  = lane & 7;         // granule slot this lane fills
  const int agran  = aslot ^ arow_l;   // logical k-granule fetched

  const int jt = t & 15, kg = t >> 4;
  const int c0 = jt * 8, k0 = kg * 4;
  const int g4 = kg >> 1, khalf = kg & 1;

  for (int kt = 0; kt < N_; kt += 64) {
    #pragma unroll
    for (int i = 0; i < 4; ++i) {
      const int row8 = (wid * 4 + i) * 8;
      const __half* src = Ag + (long)(m0 + row8 + arow_l) * N_ + kt + agran * 8;
      GLOAD_LDS16(src, As + row8 * 64);
    }
    {
      u16x8 bv[4];
      #pragma unroll
      for (int r = 0; r < 4; ++r)
        bv[r] = *reinterpret_cast<const u16x8*>(Bg + (long)(kt + k0 + r) * CC_ + c0);
      #pragma unroll
      for (int jc = 0; jc < 8; ++jc) {
        const int jj = c0 + jc;
        const int s = ((jj >> 3) & 7) ^ (jj & 7);
        ushort4 w;
        w.x = bv[0][jc]; w.y = bv[1][jc]; w.z = bv[2][jc]; w.w = bv[3][jc];
        *reinterpret_cast<ushort4*>(Bs + jj * 64 + ((g4 ^ s) << 3) + (khalf << 2)) = w;
      }
    }
    __syncthreads();
    #pragma unroll
    for (int kh = 0; kh < 2; ++kh) {
      const int gr = kh * 4 + lq;
      f16x8 af[4], bf[4];
      #pragma unroll
      for (int i = 0; i < 4; ++i) {
        const int row = wm + i * 16 + l15;
        af[i] = *reinterpret_cast<const f16x8*>(As + row * 64 + ((gr ^ (row & 7)) << 3));
      }
      #pragma unroll
      for (int jj = 0; jj < 4; ++jj) {
        const int col = wn + jj * 16 + l15;
        const int s = ((col >> 3) & 7) ^ (col & 7);
        bf[jj] = *reinterpret_cast<const f16x8*>(Bs + col * 64 + ((gr ^ s) << 3));
      }
      #pragma unroll
      for (int i = 0; i < 4; ++i)
        #pragma unroll
        for (int jj = 0; jj < 4; ++jj)
          acc[i][jj] = __builtin_amdgcn_mfma_f32_16x16x32_f16(af[i], bf[jj], acc[i][jj], 0, 0, 0);
    }
    __syncthreads();
  }
  const int cr = lq * 4, ccol = l15;
  #pragma unroll
  for (int i = 0; i < 4; ++i)
    #pragma unroll
    for (int jj = 0; jj < 4; ++jj) {
      const int grow = m0 + wm + i * 16 + cr;
      const int gcol = wn + jj * 16 + ccol;
      #pragma unroll
      for (int r = 0; r < 4; ++r)
        Cg[(long)(grow + r) * CC_ + gcol] = __float2half(acc[i][jj][r]);
    }
}

// ---------------------------------------------------------------------------
// W precompute for a node chunk: W[nloc][kc][o][i] = sum_d E[n0+nloc,d]*pool[d][kc][i][o].
template <int OSZ>
__global__ __launch_bounds__(256)
void k_wpre(const float* __restrict__ pool, const float* __restrict__ E,
            __half* __restrict__ W, int n0) {
  const int WC = 3 * OSZ * 128;
  const int col0 = blockIdx.x * 512;
  const int kc = col0 / (OSZ * 128);
  const int o0 = (col0 - kc * OSZ * 128) >> 7;
  const int t = threadIdx.x;
  __shared__ float PoolS[16 * 768];
  __shared__ float Es[32][16];
  for (int p = t; p < 512; p += 256)
    Es[p >> 4][p & 15] = E[(n0 + blockIdx.y * 32 + (p >> 4)) * 16 + (p & 15)];
  for (int p = t; p < 16 * 512; p += 256) {
    const int d = p >> 9, jl = p & 511;
    const int o = o0 + (jl >> 7), i = jl & 127;
    PoolS[d * 768 + (jl >> 3) * 12 + (jl & 7)] =
        pool[((long)(d * 3 + kc) * 128 + i) * OSZ + o];
  }
  __syncthreads();
  const int c8 = (t & 63) * 8;
  const int r0 = (t >> 6) * 8;
  const int cbase = (t & 63) * 12;
  float acc[8][8] = {};
  #pragma unroll
  for (int d = 0; d < 16; ++d) {
    const float4 pv0 = *reinterpret_cast<const float4*>(&PoolS[d * 768 + cbase]);
    const float4 pv1 = *reinterpret_cast<const float4*>(&PoolS[d * 768 + cbase + 4]);
    #pragma unroll
    for (int rr = 0; rr < 8; ++rr) {
      const float e = Es[r0 + rr][d];
      acc[rr][0] += e * pv0.x; acc[rr][1] += e * pv0.y;
      acc[rr][2] += e * pv0.z; acc[rr][3] += e * pv0.w;
      acc[rr][4] += e * pv1.x; acc[rr][5] += e * pv1.y;
      acc[rr][6] += e * pv1.z; acc[rr][7] += e * pv1.w;
    }
  }
  #pragma unroll
  for (int rr = 0; rr < 8; ++rr) {
    const int nloc = blockIdx.y * 32 + r0 + rr;
    uint4 pk;
    pk.x = pack2(acc[rr][0], acc[rr][1]);
    pk.y = pack2(acc[rr][2], acc[rr][3]);
    pk.z = pack2(acc[rr][4], acc[rr][5]);
    pk.w = pack2(acc[rr][6], acc[rr][7]);
    *reinterpret_cast<uint4*>(W + (long)nloc * WC + col0 + c8) = pk;
  }
}

// ---------------------------------------------------------------------------
// XH[b][n][0:64]=X, [64:128]=H  (fp32 -> fp16)
__global__ __launch_bounds__(256)
void k_build_xh(const float* __restrict__ X, const float* __restrict__ H,
                __half* __restrict__ XH) {
  const long i = (long)blockIdx.x * 256 + threadIdx.x;
  const long bn = i >> 5;
  const int  q  = (int)(i & 31);
  const float* src = (q < 16 ? X : H) + bn * 64 + (q & 15) * 4;
  const float4 v = *reinterpret_cast<const float4*>(src);
  ushort4 h;
  h.x = __half_as_ushort(__float2half(v.x));
  h.y = __half_as_ushort(__float2half(v.y));
  h.z = __half_as_ushort(__float2half(v.z));
  h.w = __half_as_ushort(__float2half(v.w));
  *reinterpret_cast<ushort4*>(XH + bn * CC_ + q * 4) = h;
}

// fp32 -> fp16 cast (fallback pools only)
__global__ __launch_bounds__(256)
void k_cast_f16(const float* __restrict__ src, __half* __restrict__ dst, int nquads) {
  const int i = blockIdx.x * 256 + threadIdx.x;
  if (i >= nquads) return;
  const float4 v = reinterpret_cast<const float4*>(src)[i];
  ushort4 h;
  h.x = __half_as_ushort(__float2half(v.x));
  h.y = __half_as_ushort(__float2half(v.y));
  h.z = __half_as_ushort(__float2half(v.z));
  h.w = __half_as_ushort(__float2half(v.w));
  *reinterpret_cast<ushort4*>(dst + i * 4) = h;
}

// bias[n][o] = sum_d E[n][d] * pool[d][o]
__global__ __launch_bounds__(256)
void k_bias(const float* __restrict__ E, const float* __restrict__ pool,
            float* __restrict__ bias, int O) {
  const int idx = blockIdx.x * 256 + threadIdx.x;
  const int n = idx / O, o = idx - n * O;
  float s = 0.f;
  #pragma unroll
  for (int d = 0; d < D_; ++d) s += E[n * D_ + d] * pool[d * O + o];
  bias[idx] = s;
}

// ---------------------------------------------------------------------------
// Shared staging of the data tile Ds[64b][128i] for support kc.
// kc=0: XH; kc=1: G1 (=A@XH); kc=2: 2*G2 - XH (Chebyshev, G2=A@G1).
static __device__ __forceinline__
void stage_data(int kc, const __half* XH, const __half* G1, const __half* G2,
                long base, int b, int seg, __half (*Ds)[136]) {
  if (kc < 2) {
    const uint4* s = reinterpret_cast<const uint4*>((kc ? G1 : XH) + base);
    uint4 v0 = s[0], v1 = s[1], v2 = s[2], v3 = s[3];
    uint4* d = reinterpret_cast<uint4*>(&Ds[b][seg * 32]);
    d[0] = v0; d[1] = v1; d[2] = v2; d[3] = v3;
  } else {
    const uint4* sg = reinterpret_cast<const uint4*>(G2 + base);
    const uint4* sx = reinterpret_cast<const uint4*>(XH + base);
    #pragma unroll
    for (int q = 0; q < 4; ++q) {
      uint4 g = sg[q], x = sx[q], r;
      const __half2* gh = reinterpret_cast<const __half2*>(&g);
      const __half2* xh = reinterpret_cast<const __half2*>(&x);
      __half2* rh = reinterpret_cast<__half2*>(&r);
      #pragma unroll
      for (int w = 0; w < 4; ++w) rh[w] = __hsub2(__hadd2(gh[w], gh[w]), xh[w]);
      reinterpret_cast<uint4*>(&Ds[b][seg * 32])[q] = r;
    }
  }
}

// ---------------------------------------------------------------------------
// Gate: node n = n0+blockIdx.x. ZR[64b x 128o] = sum_k XGk @ Wk + b, sigmoid;
// Z*H -> XH[...][64+o] (buffer becomes C), R -> Rbuf (fp16).
// PRE: W fragments read DIRECTLY from global (no LDS staging -- zero reuse).
template <bool PRE>
__global__ __launch_bounds__(256)
void k_gate(const __half* __restrict__ XH, const __half* __restrict__ G1,
            const __half* __restrict__ G2, const __half* __restrict__ Wsrc,
            const float* __restrict__ E, const float* __restrict__ bg,
            const float* __restrict__ H, __half* __restrict__ XHw,
            __half* __restrict__ R, int n0) {
  const int bl = blockIdx.x, n = n0 + bl;
  const int t = threadIdx.x, lane = t & 63, wid = t >> 6;
  const int l15 = lane & 15, lq = lane >> 4;
  __shared__ __half Ds[64][136];
  f32x4 acc[4][2] = {};
  if constexpr (PRE) {
    const __half* Wn = Wsrc + (long)bl * 3 * 128 * 128;
    #pragma unroll
    for (int kc = 0; kc < 3; ++kc) {
      {
        const int b = t & 63, seg = t >> 6;
        stage_data(kc, XH, G1, G2, ((long)b * N_ + n) * CC_ + seg * 32, b, seg, Ds);
      }
      __syncthreads();
      const __half* Wk = Wn + kc * 128 * 128;
      #pragma unroll
      for (int ks = 0; ks < 4; ++ks) {
        f16x8 a[4], bf[2];
        #pragma unroll
        for (int i = 0; i < 4; ++i)
          a[i] = *reinterpret_cast<const f16x8*>(&Ds[i * 16 + l15][ks * 32 + lq * 8]);
        #pragma unroll
        for (int jj = 0; jj < 2; ++jj)
          bf[jj] = *reinterpret_cast<const f16x8*>(
              Wk + (long)(wid * 32 + jj * 16 + l15) * 128 + ks * 32 + lq * 8);
        #pragma unroll
        for (int i = 0; i < 4; ++i)
          #pragma unroll
          for (int jj = 0; jj < 2; ++jj)
            acc[i][jj] = __builtin_amdgcn_mfma_f32_16x16x32_f16(a[i], bf[jj], acc[i][jj], 0, 0, 0);
      }
      __syncthreads();
    }
  } else {
    __shared__ __half Ws[128][136];
    __shared__ float es[D_];
    if (t < D_) es[t] = E[n * D_ + t];
    __syncthreads();
    #pragma unroll
    for (int kc = 0; kc < 3; ++kc) {
      {
        const int b = t & 63, seg = t >> 6;
        stage_data(kc, XH, G1, G2, ((long)b * N_ + n) * CC_ + seg * 32, b, seg, Ds);
      }
      const __half* pk = Wsrc + (long)kc * 128 * 128;
      for (int p = t; p < 64 * 128; p += 256) {
        const int o2 = p & 63, i = p >> 6;
        float w0 = 0.f, w1 = 0.f;
        #pragma unroll
        for (int d = 0; d < D_; ++d) {
          const __half2 h2 = *reinterpret_cast<const __half2*>(
              pk + (long)d * 3 * 128 * 128 + i * 128 + o2 * 2);
          const float e = es[d];
          w0 += e * __half2float(h2.x);
          w1 += e * __half2float(h2.y);
        }
        Ws[o2 * 2][i]     = __float2half(w0);
        Ws[o2 * 2 + 1][i] = __float2half(w1);
      }
      __syncthreads();
      #pragma unroll
      for (int ks = 0; ks < 4; ++ks) {
        f16x8 a[4], bf[2];
        #pragma unroll
        for (int i = 0; i < 4; ++i)
          a[i] = *reinterpret_cast<const f16x8*>(&Ds[i * 16 + l15][ks * 32 + lq * 8]);
        #pragma unroll
        for (int jj = 0; jj < 2; ++jj)
          bf[jj] = *reinterpret_cast<const f16x8*>(&Ws[wid * 32 + jj * 16 + l15][ks * 32 + lq * 8]);
        #pragma unroll
        for (int i = 0; i < 4; ++i)
          #pragma unroll
          for (int jj = 0; jj < 2; ++jj)
            acc[i][jj] = __builtin_amdgcn_mfma_f32_16x16x32_f16(a[i], bf[jj], acc[i][jj], 0, 0, 0);
      }
      __syncthreads();
    }
  }
  const int cr = lq * 4, co = l15;
  #pragma unroll
  for (int i = 0; i < 4; ++i)
    #pragma unroll
    for (int jj = 0; jj < 2; ++jj) {
      const int o = wid * 32 + jj * 16 + co;
      const float bv = bg[n * 128 + o];
      #pragma unroll
      for (int r = 0; r < 4; ++r) {
        const int b = i * 16 + cr + r;
        const float v = acc[i][jj][r] + bv;
        const float s = 1.f / (1.f + __expf(-v));
        const long base = ((long)b * N_ + n) * CO_ + (o & 63);
        if (o < 64) {
          XHw[((long)b * N_ + n) * CC_ + 64 + o] = __float2half(s * H[base]);
        } else {
          R[base] = __float2half(s);
        }
      }
    }
}

// ---------------------------------------------------------------------------
// Update: HCpre[64b x 64o] = sum_k XGk @ Wk + b; out = R*H + (1-R)*tanh(.)
template <bool PRE>
__global__ __launch_bounds__(256)
void k_update(const __half* __restrict__ C, const __half* __restrict__ G1,
              const __half* __restrict__ G2, const __half* __restrict__ Wsrc,
              const float* __restrict__ E, const float* __restrict__ bu,
              const float* __restrict__ H, const __half* __restrict__ R,
              float* __restrict__ out, int n0) {
  const int bl = blockIdx.x, n = n0 + bl;
  const int t = threadIdx.x, lane = t & 63, wid = t >> 6;
  const int l15 = lane & 15, lq = lane >> 4;
  __shared__ __half Ds[64][136];
  f32x4 acc[4] = {};
  if constexpr (PRE) {
    const __half* Wn = Wsrc + (long)bl * 3 * 64 * 128;
    #pragma unroll
    for (int kc = 0; kc < 3; ++kc) {
      {
        const int b = t & 63, seg = t >> 6;
        stage_data(kc, C, G1, G2, ((long)b * N_ + n) * CC_ + seg * 32, b, seg, Ds);
      }
      __syncthreads();
      const __half* Wk = Wn + kc * 64 * 128;
      #pragma unroll
      for (int ks = 0; ks < 4; ++ks) {
        f16x8 a[4], bf;
        #pragma unroll
        for (int i = 0; i < 4; ++i)
          a[i] = *reinterpret_cast<const f16x8*>(&Ds[i * 16 + l15][ks * 32 + lq * 8]);
        bf = *reinterpret_cast<const f16x8*>(
            Wk + (long)(wid * 16 + l15) * 128 + ks * 32 + lq * 8);
        #pragma unroll
        for (int i = 0; i < 4; ++i)
          acc[i] = __builtin_amdgcn_mfma_f32_16x16x32_f16(a[i], bf, acc[i], 0, 0, 0);
      }
      __syncthreads();
    }
  } else {
    __shared__ __half Ws[64][136];
    __shared__ float es[D_];
    if (t < D_) es[t] = E[n * D_ + t];
    __syncthreads();
    #pragma unroll
    for (int kc = 0; kc < 3; ++kc) {
      {
        const int b = t & 63, seg = t >> 6;
        stage_data(kc, C, G1, G2, ((long)b * N_ + n) * CC_ + seg * 32, b, seg, Ds);
      }
      const __half* pk = Wsrc + (long)kc * 128 * 64;
      for (int p = t; p < 32 * 128; p += 256) {
        const int o2 = p & 31, i = p >> 5;
        float w0 = 0.f, w1 = 0.f;
        #pragma unroll
        for (int d = 0; d < D_; ++d) {
          const __half2 h2 = *reinterpret_cast<const __half2*>(
              pk + (long)d * 3 * 128 * 64 + i * 64 + o2 * 2);
          const float e = es[d];
          w0 += e * __half2float(h2.x);
          w1 += e * __half2float(h2.y);
        }
        Ws[o2 * 2][i]     = __float2half(w0);
        Ws[o2 * 2 + 1][i] = __float2half(w1);
      }
      __syncthreads();
      #pragma unroll
      for (int ks = 0; ks < 4; ++ks) {
        f16x8 a[4], bf;
        #pragma unroll
        for (int i = 0; i < 4; ++i)
          a[i] = *reinterpret_cast<const f16x8*>(&Ds[i * 16 + l15][ks * 32 + lq * 8]);
        bf = *reinterpret_cast<const f16x8*>(&Ws[wid * 16 + l15][ks * 32 + lq * 8]);
        #pragma unroll
        for (int i = 0; i < 4; ++i)
          acc[i] = __builtin_amdgcn_mfma_f32_16x16x32_f16(a[i], bf, acc[i], 0, 0, 0);
      }
      __syncthreads();
    }
  }
  const int cr = lq * 4;
  const int o = wid * 16 + l15;
  const float bv = bu[n * 64 + o];
  #pragma unroll
  for (int i = 0; i < 4; ++i)
    #pragma unroll
    for (int r = 0; r < 4; ++r) {
      const int b = i * 16 + cr + r;
      const long idx = ((long)b * N_ + n) * CO_ + o;
      const float hc = tanhf(acc[i][r] + bv);
      const float rr = __half2float(R[idx]);
      out[idx] = rr * H[idx] + (1.f - rr) * hc;
    }
}

// ---------------------------------------------------------------------------
extern "C" void kernel_launch(void* const* d_in, const int* in_sizes, int n_in,
                              void* d_out, int out_size, void* d_ws, size_t ws_size,
                              hipStream_t stream) {
  const float* X  = (const float*)d_in[0];
  const float* E  = (const float*)d_in[1];
  const float* H  = (const float*)d_in[2];
  const float* gp = (const float*)d_in[3];  // [16][3][128][128]
  const float* gb = (const float*)d_in[4];  // [16][128]
  const float* up = (const float*)d_in[5];  // [16][3][128][64]
  const float* ub = (const float*)d_in[6];  // [16][64]
  float* out = (float*)d_out;

  size_t off = 0;
  auto alloc = [&](size_t bytes) {
    void* p = (char*)d_ws + off;
    off += (bytes + 255) & ~(size_t)255;
    return p;
  };
  __half* A16  = (__half*)alloc((size_t)N_ * N_ * 2);        // 8.4 MB
  __half* XH   = (__half*)alloc((size_t)B_ * N_ * CC_ * 2);  // 33.6 MB (becomes C)
  __half* G1   = (__half*)alloc((size_t)B_ * N_ * CC_ * 2);  // 33.6 MB
  __half* G2   = (__half*)alloc((size_t)B_ * N_ * CC_ * 2);  // 33.6 MB
  __half* Rb   = (__half*)alloc((size_t)B_ * N_ * CO_ * 2);  // 16.8 MB
  float*  bg   = (float*)alloc((size_t)N_ * 128 * 4);
  float*  bu   = (float*)alloc((size_t)N_ * 64 * 4);

  __half* Wbuf = (__half*)((char*)d_ws + off);
  const size_t rem = (ws_size > off) ? ws_size - off : 0;
  long cgl = (long)(rem / 98304) & ~31L;  // gate: 3*128*128*2 B per node
  long cul = (long)(rem / 49152) & ~31L;  // update: 3*64*128*2 B per node
  const int cg = (int)(cgl > N_ ? N_ : cgl);
  const int cu = (int)(cul > N_ ? N_ : cul);
  const bool pre = cg >= 32;

  const long sXH = (long)N_ * CC_;

  k_bias<<<1024, 256, 0, stream>>>(E, gb, bg, 128);
  k_bias<<<512, 256, 0, stream>>>(E, ub, bu, 64);
  k_softmaxA<<<N_, 256, 0, stream>>>(E, A16);
  k_build_xh<<<16384, 256, 0, stream>>>(X, H, XH);

  // gate propagation: G1 = A@XH, G2 = A@G1 (S2@XH = 2*G2 - XH in staging)
  k_gemm2<<<dim3(16, 1, B_), 256, 0, stream>>>(A16, XH, G1, sXH, sXH);
  k_gemm2<<<dim3(16, 1, B_), 256, 0, stream>>>(A16, G1, G2, sXH, sXH);

  __half* pg = nullptr;
  __half* pu = nullptr;
  if (pre) {
    for (int n0 = 0; n0 < N_; n0 += cg) {
      const int cnt = (N_ - n0 < cg) ? N_ - n0 : cg;
      k_wpre<128><<<dim3(96, cnt / 32), 256, 0, stream>>>(gp, E, Wbuf, n0);
      k_gate<true><<<cnt, 256, 0, stream>>>(XH, G1, G2, Wbuf, E, bg, H, XH, Rb, n0);
    }
  } else {
    pg = (__half*)alloc((size_t)D_ * 3 * 128 * 128 * 2);
    pu = (__half*)alloc((size_t)D_ * 3 * 128 * 64 * 2);
    k_cast_f16<<<768, 256, 0, stream>>>(gp, pg, 196608);
    k_cast_f16<<<384, 256, 0, stream>>>(up, pu, 98304);
    k_gate<false><<<N_, 256, 0, stream>>>(XH, G1, G2, pg, E, bg, H, XH, Rb, 0);
  }

  // update propagation (XH now holds C = [X, Z*H])
  k_gemm2<<<dim3(16, 1, B_), 256, 0, stream>>>(A16, XH, G1, sXH, sXH);
  k_gemm2<<<dim3(16, 1, B_), 256, 0, stream>>>(A16, G1, G2, sXH, sXH);

  if (pre) {
    for (int n0 = 0; n0 < N_; n0 += cu) {
      const int cnt = (N_ - n0 < cu) ? N_ - n0 : cu;
      k_wpre<64><<<dim3(48, cnt / 32), 256, 0, stream>>>(up, E, Wbuf, n0);
      k_update<true><<<cnt, 256, 0, stream>>>(XH, G1, G2, Wbuf, E, bu, H, Rb, out, n0);
    }
  } else {
    k_update<false><<<N_, 256, 0, stream>>>(XH, G1, G2, pu, E, bu, H, Rb, out, 0);
  }
}